// Round 13
// baseline (918.255 us; speedup 1.0000x reference)
//
#include <hip/hip_runtime.h>
#include <hip/hip_bf16.h>
#include <hip/hip_fp8.h>

#define DD   128
#define HH   8

typedef short bf16x8 __attribute__((ext_vector_type(8)));
typedef float f32x4  __attribute__((ext_vector_type(4)));
typedef float f32x2  __attribute__((ext_vector_type(2)));

__device__ __forceinline__ float b2f(unsigned short v){
  union { unsigned int u; float f; } x; x.u = ((unsigned int)v) << 16; return x.f;
}
__device__ __forceinline__ unsigned short f2b(float f){
  __hip_bfloat16 h = __float2bfloat16(f);
  return *(unsigned short*)&h;
}
__device__ __forceinline__ unsigned char f2f8(float x){
  __hip_fp8_e4m3 h(x);
  return h.__x;
}
__device__ __forceinline__ float f82f(unsigned char b){
  __hip_fp8_e4m3 h; h.__x = b;
  return (float)h;
}
// 4 fp8 bytes (one u32) -> 4 floats; HW packed cvt when available.
__device__ __forceinline__ void cvt4(unsigned int w, float* o){
#if defined(__has_builtin)
# if __has_builtin(__builtin_amdgcn_cvt_pk_f32_fp8)
  f32x2 lo = __builtin_amdgcn_cvt_pk_f32_fp8((int)w, false);
  f32x2 hi = __builtin_amdgcn_cvt_pk_f32_fp8((int)w, true);
  o[0]=lo[0]; o[1]=lo[1]; o[2]=hi[0]; o[3]=hi[1];
  return;
# endif
#endif
  o[0]=f82f(w&0xff); o[1]=f82f((w>>8)&0xff);
  o[2]=f82f((w>>16)&0xff); o[3]=f82f((w>>24)&0xff);
}
struct __align__(8) us4 { unsigned short x,y,z,w; };

__device__ __forceinline__ float gld(const void* p, size_t i, bool f32){
  if (f32) return ((const float*)p)[i];
  return b2f(((const unsigned short*)p)[i]);
}

// Detect input float dtype. flag=1 -> inputs are f32.
__global__ __launch_bounds__(64) void k_detect(const unsigned short* __restrict__ emb,
                                               int* __restrict__ flag){
  int t = threadIdx.x;
  float m = 0.f;
  for (int i=t; i<128; i+=64){
    float x = fabsf(b2f(emb[i]));
    if (x < 1e30f) m = fmaxf(m, x);
  }
#pragma unroll
  for (int s=1;s<64;s<<=1) m = fmaxf(m, __shfl_xor(m, s, 64));
  if (t==0) *flag = (m > 1e4f) ? 1 : 0;
}

// ALL weight blocks (8 tensors x NB matrices) -> bf16 TRANSPOSED staging, one launch.
struct WPtrs { const void* p[8]; };
__global__ __launch_bounds__(256) void w_repack16(
    WPtrs W, unsigned short* __restrict__ stage, int NBt,
    const int* __restrict__ dflag)
{
  const bool wf32 = (*dflag) != 0;
  int idx = blockIdx.x >> 6;
  int ti = idx / NBt, bi = idx - ti*NBt;
  size_t bo = (size_t)bi*DD*DD;
  int i = (blockIdx.x & 63)*256 + threadIdx.x;
  int k = i >> 7, n = i & 127;
  float x;
  if (wf32) x = ((const float*)W.p[ti])[bo + i];
  else      x = b2f(((const unsigned short*)W.p[ti])[bo + i]);
  stage[(size_t)idx*DD*DD + n*DD + k] = f2b(x);
}

enum { EPI_STORE=0, EPI_SCALE_CONST=1, EPI_SCALE_GATHER=2, EPI_RELU=3,
       EPI_RELU_RES=4 };

#define APAD 136
#define CPAD 132

// C[M,128] = epi( prologue(A)[M,128] @ B[128,128] ), B bf16 TRANSPOSED ([n][k]).
template<int EPI, bool NORM, bool INB, bool OUTB>
__global__ __launch_bounds__(256) void gemm128m(
    const void* __restrict__ Av, const unsigned short* __restrict__ Bt,
    void* __restrict__ Cv, int M,
    const float* __restrict__ z, const float* __restrict__ svec,
    const float* __restrict__ P2, const int* __restrict__ gidx,
    const unsigned short* __restrict__ Rb)
{
  __shared__ unsigned short Asb[64*APAD];
  __shared__ unsigned short Btb[128*APAD];
  const int tid = threadIdx.x;
  const int wave = tid >> 6, lane = tid & 63;
  const int row0 = blockIdx.x * 64;

  {
    int r = tid >> 2, cb = (tid & 3) * 32;
    int gr = row0 + r;
    if (INB){
      const unsigned short* Ab = (const unsigned short*)Av;
#pragma unroll
      for (int j=0;j<4;j++){
        int c = cb + j*8;
        uint4 raw = make_uint4(0,0,0,0);
        if (gr < M) raw = *(const uint4*)(Ab + (size_t)gr*DD + c);
        if (NORM){
          float s = 0.f;
          if (gr < M) s = 1.0f/(z[(size_t)gr*HH + (c>>4)] + 1e-9f);
          const unsigned short* hw = (const unsigned short*)&raw;
          us4 o0, o1;
          o0.x=f2b(b2f(hw[0])*s); o0.y=f2b(b2f(hw[1])*s);
          o0.z=f2b(b2f(hw[2])*s); o0.w=f2b(b2f(hw[3])*s);
          o1.x=f2b(b2f(hw[4])*s); o1.y=f2b(b2f(hw[5])*s);
          o1.z=f2b(b2f(hw[6])*s); o1.w=f2b(b2f(hw[7])*s);
          *(us4*)&Asb[r*APAD + c] = o0; *(us4*)&Asb[r*APAD + c + 4] = o1;
        } else {
          *(uint4*)&Asb[r*APAD + c] = raw;
        }
      }
    } else {
      const float* Af = (const float*)Av;
#pragma unroll
      for (int j=0;j<8;j++){
        int c = cb + j*4;
        float4 val = make_float4(0.f,0.f,0.f,0.f);
        if (gr < M){
          val = *(const float4*)(Af + (size_t)gr*DD + c);
          if (NORM){
            float s = 1.0f / (z[(size_t)gr*HH + (c>>4)] + 1e-9f);
            val.x*=s; val.y*=s; val.z*=s; val.w*=s;
          }
        }
        us4 o; o.x=f2b(val.x); o.y=f2b(val.y); o.z=f2b(val.z); o.w=f2b(val.w);
        *(us4*)&Asb[r*APAD + c] = o;
      }
    }
  }
  {
    int n = tid >> 1, k0s = (tid & 1) * 64;
#pragma unroll
    for (int j=0;j<8;j++){
      uint4 raw = *(const uint4*)(Bt + (size_t)n*DD + k0s + j*8);
      *(uint4*)&Btb[n*APAD + k0s + j*8] = raw;
    }
  }
  __syncthreads();

  f32x4 acc[8];
#pragma unroll
  for (int t=0;t<8;t++) acc[t] = (f32x4){0.f,0.f,0.f,0.f};
  const int am = (lane & 15), kq = (lane >> 4) * 8;
#pragma unroll
  for (int k0=0;k0<128;k0+=32){
    bf16x8 a = *(bf16x8*)&Asb[(wave*16 + am)*APAD + k0 + kq];
#pragma unroll
    for (int t=0;t<8;t++){
      bf16x8 b = *(bf16x8*)&Btb[(t*16 + am)*APAD + k0 + kq];
      acc[t] = __builtin_amdgcn_mfma_f32_16x16x32_bf16(a, b, acc[t], 0,0,0);
    }
  }
  __syncthreads();
  float* Cls = (float*)Btb;
  {
    int rr = wave*16 + (lane>>4)*4;
    int cc = lane & 15;
#pragma unroll
    for (int t=0;t<8;t++)
#pragma unroll
      for (int r=0;r<4;r++)
        Cls[(rr + r)*CPAD + t*16 + cc] = acc[t][r];
  }
  __syncthreads();

  {
    int r = tid >> 2, cb = (tid & 3) * 32;
    int gr = row0 + r;
    if (gr < M){
#pragma unroll
      for (int j=0;j<8;j++){
        int c = cb + j*4;
        float4 o = *(float4*)&Cls[r*CPAD + c];
        if (EPI == EPI_SCALE_CONST){
          o.x*=svec[c+0]; o.y*=svec[c+1]; o.z*=svec[c+2]; o.w*=svec[c+3];
        } else if (EPI == EPI_SCALE_GATHER){
          int g = gidx[gr];
          const float* p = P2 + (size_t)g*DD + c;
          o.x*=(svec[c+0]+p[0]); o.y*=(svec[c+1]+p[1]);
          o.z*=(svec[c+2]+p[2]); o.w*=(svec[c+3]+p[3]);
        } else if (EPI == EPI_RELU){
          o.x=fmaxf(o.x,0.f); o.y=fmaxf(o.y,0.f); o.z=fmaxf(o.z,0.f); o.w=fmaxf(o.w,0.f);
        } else if (EPI == EPI_RELU_RES){
          us4 rb = *(const us4*)(Rb + (size_t)gr*DD + c);
          o.x=fmaxf(o.x,0.f)+b2f(rb.x); o.y=fmaxf(o.y,0.f)+b2f(rb.y);
          o.z=fmaxf(o.z,0.f)+b2f(rb.z); o.w=fmaxf(o.w,0.f)+b2f(rb.w);
        }
        if (OUTB){
          us4 ob; ob.x=f2b(o.x); ob.y=f2b(o.y); ob.z=f2b(o.z); ob.w=f2b(o.w);
          *(us4*)((unsigned short*)Cv + (size_t)gr*DD + c) = ob;
        } else {
          *(float4*)((float*)Cv + (size_t)gr*DD + c) = o;
        }
      }
    }
  }
}

// Meta Wo gemm + residual + FUSED MN-learner.
// meta_feat += relu(norm(agg_m)@Wo); p2mn/p1mn = learner(relu vals).
__global__ __launch_bounds__(256) void gemm_wo_meta(
    const float* __restrict__ Af, const unsigned short* __restrict__ Bt, int M,
    const float* __restrict__ z, float* __restrict__ meta_feat,
    const void* __restrict__ u, const void* __restrict__ W2,
    const void* __restrict__ W1,
    float* __restrict__ p2mn, float* __restrict__ p1mn,
    const int* __restrict__ dflag)
{
  __shared__ unsigned short Asb[64*APAD];
  __shared__ unsigned short Btb[128*APAD];
  const bool wf32 = (*dflag) != 0;
  const int tid = threadIdx.x;
  const int wave = tid >> 6, lane = tid & 63;
  const int row0 = blockIdx.x * 64;

  {
    int r = tid >> 2, cb = (tid & 3) * 32;
    int gr = row0 + r;
#pragma unroll
    for (int j=0;j<8;j++){
      int c = cb + j*4;
      float4 val = make_float4(0.f,0.f,0.f,0.f);
      if (gr < M){
        val = *(const float4*)(Af + (size_t)gr*DD + c);
        float s = 1.0f / (z[(size_t)gr*HH + (c>>4)] + 1e-9f);
        val.x*=s; val.y*=s; val.z*=s; val.w*=s;
      }
      us4 o; o.x=f2b(val.x); o.y=f2b(val.y); o.z=f2b(val.z); o.w=f2b(val.w);
      *(us4*)&Asb[r*APAD + c] = o;
    }
  }
  {
    int n = tid >> 1, k0s = (tid & 1) * 64;
#pragma unroll
    for (int j=0;j<8;j++){
      uint4 raw = *(const uint4*)(Bt + (size_t)n*DD + k0s + j*8);
      *(uint4*)&Btb[n*APAD + k0s + j*8] = raw;
    }
  }
  __syncthreads();

  f32x4 acc[8];
#pragma unroll
  for (int t=0;t<8;t++) acc[t] = (f32x4){0.f,0.f,0.f,0.f};
  const int am = (lane & 15), kq = (lane >> 4) * 8;
#pragma unroll
  for (int k0=0;k0<128;k0+=32){
    bf16x8 a = *(bf16x8*)&Asb[(wave*16 + am)*APAD + k0 + kq];
#pragma unroll
    for (int t=0;t<8;t++){
      bf16x8 b = *(bf16x8*)&Btb[(t*16 + am)*APAD + k0 + kq];
      acc[t] = __builtin_amdgcn_mfma_f32_16x16x32_bf16(a, b, acc[t], 0,0,0);
    }
  }
  __syncthreads();
  float* Cls = (float*)Btb;
  {
    int rr = wave*16 + (lane>>4)*4;
    int cc = lane & 15;
#pragma unroll
    for (int t=0;t<8;t++)
#pragma unroll
      for (int r=0;r<4;r++)
        Cls[(rr + r)*CPAD + t*16 + cc] = acc[t][r];
  }
  __syncthreads();

  {
    int r = tid >> 2, cb = (tid & 3) * 32;
    int gr = row0 + r;
    float x[32];
    if (gr < M){
      // relu + residual; keep relu vals for the learner
#pragma unroll
      for (int j=0;j<8;j++){
        int c = cb + j*4;
        float4 o = *(float4*)&Cls[r*CPAD + c];
        o.x=fmaxf(o.x,0.f); o.y=fmaxf(o.y,0.f); o.z=fmaxf(o.z,0.f); o.w=fmaxf(o.w,0.f);
        x[j*4+0]=o.x; x[j*4+1]=o.y; x[j*4+2]=o.z; x[j*4+3]=o.w;
        float4 rf = *(const float4*)(meta_feat + (size_t)gr*DD + c);
        *(float4*)(meta_feat + (size_t)gr*DD + c) =
            make_float4(o.x+rf.x, o.y+rf.y, o.z+rf.z, o.w+rf.w);
      }
      // learner: 4 lanes per row (lanes r*4..r*4+3 are consecutive within wave)
      float swl[16]; float ssum = 0.f;
#pragma unroll
      for (int l=0;l<16;l++){
        float part = 0.f;
#pragma unroll
        for (int j=0;j<32;j++) part += x[j]*gld(u, l*128 + cb + j, wf32);
        part += __shfl_xor(part, 1, 64);
        part += __shfl_xor(part, 2, 64);
        float e = __expf(part * 0.08838834764831845f);
        swl[l] = e; ssum += e;
      }
      float inv = 1.f/ssum;
#pragma unroll
      for (int j=0;j<32;j++){
        float a = 0.f;
#pragma unroll
        for (int l=0;l<16;l++) a += swl[l]*gld(W2, l*128 + cb + j, wf32);
        p2mn[(size_t)gr*DD + cb + j] = a*inv;
      }
      if ((tid & 3) == 0){
#pragma unroll
        for (int h=0;h<8;h++){
          float a = 0.f;
#pragma unroll
          for (int l=0;l<16;l++) a += swl[l]*gld(W1, l*8 + h, wf32);
          p1mn[(size_t)gr*HH + h] = a*inv;
        }
      }
    }
  }
}

// Fused Q/K/V gemm. FP8KV: phases 1/2 write fp8 (x8 scale) into 256B/row kv buffer.
template<int EPIQ, bool INB, bool FP8KV>
__global__ __launch_bounds__(256) void gemm_qkv(
    const void* __restrict__ Av,
    const unsigned short* __restrict__ Btq, const unsigned short* __restrict__ Btk,
    const unsigned short* __restrict__ Btv,
    void* __restrict__ Cq, void* __restrict__ Ck, int stK,
    void* __restrict__ Cvo, int stV, int M,
    const float* __restrict__ svec, const float* __restrict__ P2,
    const int* __restrict__ gidx)
{
  __shared__ unsigned short Asb[64*APAD];
  __shared__ unsigned short Btb[128*APAD];
  const int tid = threadIdx.x;
  const int wave = tid >> 6, lane = tid & 63;
  const int row0 = blockIdx.x * 64;

  {
    int r = tid >> 2, cb = (tid & 3) * 32;
    int gr = row0 + r;
    if (INB){
      const unsigned short* Ab = (const unsigned short*)Av;
#pragma unroll
      for (int j=0;j<4;j++){
        int c = cb + j*8;
        uint4 raw = make_uint4(0,0,0,0);
        if (gr < M) raw = *(const uint4*)(Ab + (size_t)gr*DD + c);
        *(uint4*)&Asb[r*APAD + c] = raw;
      }
    } else {
      const float* Af = (const float*)Av;
#pragma unroll
      for (int j=0;j<8;j++){
        int c = cb + j*4;
        float4 val = make_float4(0.f,0.f,0.f,0.f);
        if (gr < M) val = *(const float4*)(Af + (size_t)gr*DD + c);
        us4 o; o.x=f2b(val.x); o.y=f2b(val.y); o.z=f2b(val.z); o.w=f2b(val.w);
        *(us4*)&Asb[r*APAD + c] = o;
      }
    }
  }

  const unsigned short* Bts[3] = {Btq, Btk, Btv};
  void* Cs[3] = {Cq, Ck, Cvo};
  const int sts[3] = {DD, stK, stV};
  const int am = (lane & 15), kq = (lane >> 4) * 8;

  for (int ph=0; ph<3; ph++){
    {
      int n = tid >> 1, k0s = (tid & 1) * 64;
      const unsigned short* Bt = Bts[ph];
#pragma unroll
      for (int j=0;j<8;j++){
        uint4 raw = *(const uint4*)(Bt + (size_t)n*DD + k0s + j*8);
        *(uint4*)&Btb[n*APAD + k0s + j*8] = raw;
      }
    }
    __syncthreads();
    f32x4 acc[8];
#pragma unroll
    for (int t=0;t<8;t++) acc[t] = (f32x4){0.f,0.f,0.f,0.f};
#pragma unroll
    for (int k0=0;k0<128;k0+=32){
      bf16x8 a = *(bf16x8*)&Asb[(wave*16 + am)*APAD + k0 + kq];
#pragma unroll
      for (int t=0;t<8;t++){
        bf16x8 b = *(bf16x8*)&Btb[(t*16 + am)*APAD + k0 + kq];
        acc[t] = __builtin_amdgcn_mfma_f32_16x16x32_bf16(a, b, acc[t], 0,0,0);
      }
    }
    __syncthreads();
    float* Cls = (float*)Btb;
    {
      int rr = wave*16 + (lane>>4)*4;
      int cc = lane & 15;
#pragma unroll
      for (int t=0;t<8;t++)
#pragma unroll
        for (int r=0;r<4;r++)
          Cls[(rr + r)*CPAD + t*16 + cc] = acc[t][r];
    }
    __syncthreads();
    {
      int r = tid >> 2, cb = (tid & 3) * 32;
      int gr = row0 + r;
      if (gr < M){
#pragma unroll
        for (int j=0;j<8;j++){
          int c = cb + j*4;
          float4 o = *(float4*)&Cls[r*CPAD + c];
          if (ph == 0){
            if (EPIQ == EPI_SCALE_GATHER){
              int g = gidx[gr];
              const float* p = P2 + (size_t)g*DD + c;
              o.x*=(svec[c+0]+p[0]); o.y*=(svec[c+1]+p[1]);
              o.z*=(svec[c+2]+p[2]); o.w*=(svec[c+3]+p[3]);
            } else {
              o.x*=svec[c+0]; o.y*=svec[c+1]; o.z*=svec[c+2]; o.w*=svec[c+3];
            }
          }
          if (FP8KV && ph > 0){
            unsigned char* Cb = (unsigned char*)Cs[ph];
            uchar4 ob;
            ob.x=f2f8(o.x*8.f); ob.y=f2f8(o.y*8.f);
            ob.z=f2f8(o.z*8.f); ob.w=f2f8(o.w*8.f);
            *(uchar4*)(Cb + (size_t)gr*256 + c) = ob;
          } else {
            us4 ob; ob.x=f2b(o.x); ob.y=f2b(o.y); ob.z=f2b(o.z); ob.w=f2b(o.w);
            *(us4*)((unsigned short*)Cs[ph] + (size_t)gr*sts[ph] + c) = ob;
          }
        }
      }
    }
    __syncthreads();
  }
}

// Static param-name graph -> base params.
__global__ __launch_bounds__(256) void k_static(
    const void* __restrict__ emb, const int* __restrict__ svals,
    const int* __restrict__ ssrc, const int* __restrict__ sdst,
    const void* __restrict__ u, const void* __restrict__ W2,
    const void* __restrict__ W1, float* __restrict__ base, int nsrc,
    const int* __restrict__ dflag)
{
  __shared__ float sagg[15][128];
  __shared__ float ssc[15][16];
  __shared__ float sww[15][16];
  const bool wf32 = (*dflag) != 0;
  const int t = threadIdx.x;
  for (int i=t;i<15*128;i+=256) ((float*)sagg)[i]=0.f;
  __syncthreads();
  if (t < 128){
    for (int i=0;i<nsrc;i++){
      int row = sdst[i]; int vr = svals[ssrc[i]];
      sagg[row][t] += gld(emb, (size_t)vr*DD + t, wf32);
    }
  }
  __syncthreads();
  if (t < 240){
    int n = t>>4, l = t&15;
    float a=0.f;
    for (int d=0;d<128;d++) a += sagg[n][d]*gld(u, l*128+d, wf32);
    ssc[n][l] = a * 0.08838834764831845f;
  }
  __syncthreads();
  if (t < 15){
    float mx=-1e30f;
    for (int l=0;l<16;l++) mx = fmaxf(mx, ssc[t][l]);
    float s=0.f;
    for (int l=0;l<16;l++){ float e=__expf(ssc[t][l]-mx); sww[t][l]=e; s+=e; }
    float inv = 1.f/s;
    for (int l=0;l<16;l++) sww[t][l]*=inv;
  }
  __syncthreads();
  if (t < 8){
    float a=0.f,b=0.f,c=0.f;
    for (int l=0;l<16;l++){
      float wv = gld(W1, l*8+t, wf32);
      a += sww[0][l]*wv; b += sww[3][l]*wv; c += sww[9][l]*wv;
    }
    base[t]=a; base[8+t]=b; base[16+t]=c;
  }
  if (t < 128){
    float a=0.f,b=0.f;
    for (int l=0;l<16;l++){
      float wv = gld(W2, l*128+t, wf32);
      a += sww[6][l]*wv; b += sww[12][l]*wv;
    }
    base[24+t]=a; base[152+t]=b;
  }
}

// Merged gather: big graph rows -> bf16 feat; meta rows -> f32 meta_feat.
__global__ __launch_bounds__(256) void gather_rows2(
    const void* __restrict__ emb,
    const int* __restrict__ valsB, unsigned short* __restrict__ featB, int nB,
    const int* __restrict__ valsM, float* __restrict__ featM, int nM,
    const int* __restrict__ dflag)
{
  const bool wf32 = (*dflag) != 0;
  int i = blockIdx.x*256 + threadIdx.x;
  bool big = (i < nB*16);
  int i2 = big ? i : (i - nB*16);
  if (!big && i2 >= nM*16) return;
  int r = i2>>4, c = (i2&15)*8;
  int vr = big ? valsB[r] : valsM[r];
  float vb[8];
  if (wf32){
    float4 f0 = *(const float4*)((const float*)emb + (size_t)vr*DD + c);
    float4 f1 = *(const float4*)((const float*)emb + (size_t)vr*DD + c + 4);
    vb[0]=f0.x; vb[1]=f0.y; vb[2]=f0.z; vb[3]=f0.w;
    vb[4]=f1.x; vb[5]=f1.y; vb[6]=f1.z; vb[7]=f1.w;
  } else {
    uint4 raw = *(const uint4*)((const unsigned short*)emb + (size_t)vr*DD + c);
    const unsigned short* hw = (const unsigned short*)&raw;
#pragma unroll
    for (int j=0;j<8;j++) vb[j] = b2f(hw[j]);
  }
  if (big){
    unsigned short* d = featB + (size_t)r*DD + c;
    us4 o0, o1;
    o0.x=f2b(vb[0]); o0.y=f2b(vb[1]); o0.z=f2b(vb[2]); o0.w=f2b(vb[3]);
    o1.x=f2b(vb[4]); o1.y=f2b(vb[5]); o1.z=f2b(vb[6]); o1.w=f2b(vb[7]);
    *(us4*)d = o0; *(us4*)(d+4) = o1;
  } else {
    float* d = featM + (size_t)r*DD + c;
    *(float4*)d     = make_float4(vb[0],vb[1],vb[2],vb[3]);
    *(float4*)(d+4) = make_float4(vb[4],vb[5],vb[6],vb[7]);
  }
}

__global__ __launch_bounds__(256) void zeroi(int* __restrict__ p, int n){
  int i = blockIdx.x*256 + threadIdx.x;
  if (i < n) p[i] = 0;
}

// ---------------- merged CSR build (big + meta graphs) ----------------
__global__ __launch_bounds__(256) void k_hist2(
    const int* __restrict__ dstB, const int* __restrict__ dstM,
    int* __restrict__ degB, int* __restrict__ degM, int E, int ME, int nbE){
  int b = blockIdx.x, t = threadIdx.x;
  if (b < nbE){ int i = b*256+t; if (i < E) atomicAdd(&degB[dstB[i]], 1); }
  else { int i = (b-nbE)*256+t; if (i < ME) atomicAdd(&degM[dstM[i]], 1); }
}

__global__ __launch_bounds__(256) void k_scan1b(
    const int* __restrict__ degB, int* __restrict__ rpB, int* __restrict__ bsB,
    int nB, int nbB,
    const int* __restrict__ degM, int* __restrict__ rpM, int* __restrict__ bsM,
    int nM){
  __shared__ int ls[256];
  int blk = blockIdx.x, t = threadIdx.x;
  const int* deg; int* rowptr; int* bsum; int n; int b;
  if (blk < nbB){ deg=degB; rowptr=rpB; bsum=bsB; n=nB; b=blk; }
  else          { deg=degM; rowptr=rpM; bsum=bsM; n=nM; b=blk-nbB; }
  int base = b*1024 + t*4;
  int v0 = (base+0<n)?deg[base+0]:0;
  int v1 = (base+1<n)?deg[base+1]:0;
  int v2 = (base+2<n)?deg[base+2]:0;
  int v3 = (base+3<n)?deg[base+3]:0;
  int tsum = v0+v1+v2+v3;
  ls[t] = tsum; __syncthreads();
  for (int o=1;o<256;o<<=1){
    int x = (t>=o) ? ls[t-o] : 0;
    __syncthreads();
    ls[t] += x;
    __syncthreads();
  }
  int excl = ls[t]-tsum;
  if (t==255) bsum[b] = ls[255];
  if (base+0<n) rowptr[base+0]=excl;
  if (base+1<n) rowptr[base+1]=excl+v0;
  if (base+2<n) rowptr[base+2]=excl+v0+v1;
  if (base+3<n) rowptr[base+3]=excl+v0+v1+v2;
}

// scan3 with in-block prefix of block sums (scan2 merged in).
__global__ __launch_bounds__(256) void k_scan3b(
    int* __restrict__ rpB, const int* __restrict__ bsB, int* __restrict__ curB,
    int nB, int nb3B, int nbsB,
    int* __restrict__ rpM, const int* __restrict__ bsM, int* __restrict__ curM,
    int nM, int nbsM){
  __shared__ int spre;
  int blk = blockIdx.x, t = threadIdx.x;
  if (blk < nb3B){
    if (t == 0){
      int chunk = blk >> 2;     // 256-thread block covers 1/4 of a 1024 chunk
      int pre = 0;
      for (int j=0;j<chunk;j++) pre += bsB[j];
      spre = pre;
      if (blk == 0){
        int tot = 0;
        for (int j=0;j<nbsB;j++) tot += bsB[j];
        rpB[nB] = tot;
      }
    }
    __syncthreads();
    int i = blk*256 + t;
    if (i < nB){ int r = rpB[i] + spre; rpB[i] = r; curB[i] = r; }
  } else {
    int b2 = blk - nb3B;
    if (t == 0){
      int chunk = b2 >> 2;
      int pre = 0;
      for (int j=0;j<chunk;j++) pre += bsM[j];
      spre = pre;
      if (b2 == 0){
        int tot = 0;
        for (int j=0;j<nbsM;j++) tot += bsM[j];
        rpM[nM] = tot;
      }
    }
    __syncthreads();
    int i = b2*256 + t;
    if (i < nM){ int r = rpM[i] + spre; rpM[i] = r; curM[i] = r; }
  }
}

// scatter. Big graph: pack (src | meid<<17) into one int.
__global__ __launch_bounds__(256) void k_scatter2(
    const int* __restrict__ dstB, const int* __restrict__ srcB,
    const int* __restrict__ auxB, int* __restrict__ curB,
    int* __restrict__ epackB, int E, int nbE,
    const int* __restrict__ dstM, const int* __restrict__ srcM,
    int* __restrict__ curM, int* __restrict__ esrcM, int* __restrict__ eauxM,
    int ME){
  int blk = blockIdx.x, t = threadIdx.x;
  if (blk < nbE){
    int e = blk*256 + t;
    if (e < E){
      int p = atomicAdd(&curB[dstB[e]], 1);
      epackB[p] = srcB[e] | (auxB[e] << 17);
    }
  } else {
    int e = (blk-nbE)*256 + t;
    if (e < ME){
      int p = atomicAdd(&curM[dstM[e]], 1);
      esrcM[p] = srcM[e];
      eauxM[p] = e;
    }
  }
}

// ---------------- meta-graph edges: CSR + FUSED ME-learner ----------------
// Computes z_m/agg_m AND w2me = bf16(base_e2 + learner2d(ke)), p1me = learner1d(ke).
__global__ __launch_bounds__(256) void edge_meta_csr(
    const int* __restrict__ rowptr, const int* __restrict__ esrc,
    const int* __restrict__ eorig,
    const unsigned short* __restrict__ qm, const unsigned short* __restrict__ kfm,
    const unsigned short* __restrict__ vm,
    const float* __restrict__ base,
    const void* __restrict__ u, const void* __restrict__ W2,
    const void* __restrict__ W1,
    unsigned short* __restrict__ w2me, unsigned short* __restrict__ p1me,
    float* __restrict__ z, float* __restrict__ agg, int NM,
    const int* __restrict__ dflag)
{
  int d = blockIdx.x*4 + (threadIdx.x>>6);
  if (d >= NM) return;
  const bool wf32 = (*dflag) != 0;
  int lane = threadIdx.x & 63;
  const float* be2 = base+152; const float* be1 = base+16; const float* bn1 = base+8;
  size_t dq = (size_t)d*DD;
  float q0 = b2f(qm[dq+lane]), q1 = b2f(qm[dq+64+lane]);
  float w0 = be2[lane], w1 = be2[64+lane];
  int h0 = lane>>4, h1 = h0+4;
  float bias0 = be1[h0] + bn1[h0];
  float bias1 = be1[h1] + bn1[h1];
  float z0=0.f, z1=0.f, a0=0.f, a1=0.f;
  int i0 = rowptr[d], i1 = rowptr[d+1];
  for (int i=i0; i<i1; i++){
    int s = esrc[i], e = eorig[i];
    size_t so=(size_t)s*DD, eo=(size_t)e*DD;
    float ke0 = b2f(kfm[so+lane])    * w0;
    float ke1 = b2f(kfm[so+64+lane]) * w1;
    // attention score path
    float p0 = q0*ke0, p1 = q1*ke1;
#pragma unroll
    for (int m=1;m<16;m<<=1){ p0 += __shfl_xor(p0,m,64); p1 += __shfl_xor(p1,m,64); }
    float e0 = __expf(p0*0.25f + bias0);
    float e1 = __expf(p1*0.25f + bias1);
    z0 += e0; z1 += e1;
    a0 += e0*b2f(vm[so+lane]);
    a1 += e1*b2f(vm[so+64+lane]);
    // fused edge-learner: st[l] = (ke . u[l]) / sqrt(128); softmax; W2/W1 mix
    float swl[16]; float ssum = 0.f;
#pragma unroll
    for (int l=0;l<16;l++){
      float part = ke0*gld(u, l*128+lane, wf32) + ke1*gld(u, l*128+64+lane, wf32);
#pragma unroll
      for (int m=1;m<64;m<<=1) part += __shfl_xor(part, m, 64);
      float ex = __expf(part * 0.08838834764831845f);
      swl[l] = ex; ssum += ex;
    }
    float inv = 1.f/ssum;
    float o0 = base[152+lane], o1 = base[152+64+lane];
    float pp = 0.f;
#pragma unroll
    for (int l=0;l<16;l++){
      float sv = swl[l]*inv;
      o0 += sv*gld(W2, l*128+lane, wf32);
      o1 += sv*gld(W2, l*128+64+lane, wf32);
      if (lane < 8) pp += sv*gld(W1, l*8+lane, wf32);
    }
    w2me[eo+lane]    = f2b(o0);
    w2me[eo+64+lane] = f2b(o1);
    if (lane < 8) p1me[(size_t)e*HH+lane] = f2b(pp);
  }
  if ((lane&15)==0){ z[(size_t)d*HH+h0] = z0; z[(size_t)d*HH+h1] = z1; }
  agg[dq+lane]    = a0;
  agg[dq+64+lane] = a1;
}

// ---------------- big-graph: fused scores+agg, fp8 kv, packed indices ----------
__global__ __launch_bounds__(256) void edge_fused(
    const int* __restrict__ rowptr, const int* __restrict__ epack,
    const int* __restrict__ mnid,
    const unsigned short* __restrict__ q, const unsigned char* __restrict__ kv8,
    const unsigned short* __restrict__ w2me, const unsigned short* __restrict__ p1me,
    const float* __restrict__ p1mn, const float* __restrict__ base,
    float* __restrict__ z, unsigned short* __restrict__ aggb, int N)
{
  int wv = blockIdx.x*4 + (threadIdx.x>>6);
  int d0 = wv*4;
  if (d0 >= N) return;
  int lane = threadIdx.x & 63;
  int grp = lane >> 4, l16 = lane & 15;
  int c8 = l16 * 8;
  int h = l16 >> 1;
  const float* be1 = base+16; const float* bn1 = base+8;
  const float biash = be1[h] + bn1[h];

  for (int dd=0; dd<4; dd++){
    int d = d0 + dd;
    if (d >= N) break;
    size_t dq = (size_t)d*DD;
    float qv[8];
    {
      uint4 qraw = *(const uint4*)(q + dq + c8);
      const unsigned short* qh = (const unsigned short*)&qraw;
#pragma unroll
      for (int j=0;j<8;j++) qv[j] = b2f(qh[j])*0.03125f;  // 0.25 * 1/8 (k fp8 scale)
    }
    int mn = mnid[d];
    float bias = biash + p1mn[(size_t)mn*HH + h];

    float zh = 0.f;
    float a[8];
#pragma unroll
    for (int j=0;j<8;j++) a[j] = 0.f;

    int i0 = rowptr[d], i1 = rowptr[d+1];
    int i = i0 + grp;
    for (; i + 4 < i1; i += 8){
      unsigned int v0p = (unsigned int)epack[i];
      unsigned int v1p = (unsigned int)epack[i+4];
      int s0 = v0p & 0x1FFFF, me0 = v0p >> 17;
      int s1 = v1p & 0x1FFFF, me1 = v1p >> 17;
      size_t kvo0 = (size_t)s0*256, mo0 = (size_t)me0*DD;
      size_t kvo1 = (size_t)s1*256, mo1 = (size_t)me1*DD;
      uint2 kraw0 = *(const uint2*)(kv8 + kvo0 + c8);
      uint2 vraw0 = *(const uint2*)(kv8 + kvo0 + 128 + c8);
      uint4 wraw0 = *(const uint4*)(w2me + mo0 + c8);
      float pm0 = b2f(p1me[(size_t)me0*HH + h]);
      uint2 kraw1 = *(const uint2*)(kv8 + kvo1 + c8);
      uint2 vraw1 = *(const uint2*)(kv8 + kvo1 + 128 + c8);
      uint4 wraw1 = *(const uint4*)(w2me + mo1 + c8);
      float pm1 = b2f(p1me[(size_t)me1*HH + h]);
      float k0f[8], v0f[8], k1f[8], v1f[8];
      cvt4(kraw0.x, k0f); cvt4(kraw0.y, k0f+4);
      cvt4(vraw0.x, v0f); cvt4(vraw0.y, v0f+4);
      cvt4(kraw1.x, k1f); cvt4(kraw1.y, k1f+4);
      cvt4(vraw1.x, v1f); cvt4(vraw1.y, v1f+4);
      const unsigned short* wh0 = (const unsigned short*)&wraw0;
      const unsigned short* wh1 = (const unsigned short*)&wraw1;
      float pA = 0.f, pB = 0.f;
#pragma unroll
      for (int j=0;j<8;j++){
        pA += qv[j]*(k0f[j]*b2f(wh0[j]));
        pB += qv[j]*(k1f[j]*b2f(wh1[j]));
      }
      pA += __shfl_xor(pA, 1, 64);
      pB += __shfl_xor(pB, 1, 64);
      float ex0 = __expf(pA + bias + pm0);
      float ex1 = __expf(pB + bias + pm1);
      zh += ex0 + ex1;
      float ev0 = ex0*0.125f, ev1 = ex1*0.125f;
#pragma unroll
      for (int j=0;j<8;j++) a[j] += ev0*v0f[j] + ev1*v1f[j];
    }
    if (i < i1){
      unsigned int vp = (unsigned int)epack[i];
      int s = vp & 0x1FFFF, me = vp >> 17;
      size_t kvo = (size_t)s*256, mo = (size_t)me*DD;
      uint2 kraw = *(const uint2*)(kv8 + kvo + c8);
      uint2 vraw = *(const uint2*)(kv8 + kvo + 128 + c8);
      uint4 wraw = *(const uint4*)(w2me + mo + c8);
      float pm = b2f(p1me[(size_t)me*HH + h]);
      float kf[8], vf[8];
      cvt4(kraw.x, kf); cvt4(kraw.y, kf+4);
      cvt4(vraw.x, vf); cvt4(vraw.y, vf+4);
      const unsigned short* wh = (const unsigned short*)&wraw;
      float p = 0.f;
#pragma unroll
      for (int j=0;j<8;j++) p += qv[j]*(kf[j]*b2f(wh[j]));
      p += __shfl_xor(p, 1, 64);
      float ex = __expf(p + bias + pm);
      zh += ex;
      float ev = ex*0.125f;
#pragma unroll
      for (int j=0;j<8;j++) a[j] += ev*vf[j];
    }

    zh += __shfl_xor(zh, 16, 64); zh += __shfl_xor(zh, 32, 64);
#pragma unroll
    for (int j=0;j<8;j++){
      a[j] += __shfl_xor(a[j], 16, 64);
      a[j] += __shfl_xor(a[j], 32, 64);
    }
    if (grp == 0){
      us4 o0, o1;
      o0.x=f2b(a[0]); o0.y=f2b(a[1]); o0.z=f2b(a[2]); o0.w=f2b(a[3]);
      o1.x=f2b(a[4]); o1.y=f2b(a[5]); o1.z=f2b(a[6]); o1.w=f2b(a[7]);
      *(us4*)(aggb + dq + c8)     = o0;
      *(us4*)(aggb + dq + c8 + 4) = o1;
      if ((l16 & 1) == 0) z[(size_t)d*HH + h] = zh;
    }
  }
}

// One 16-lane group per target; vectorized feat row read + shuffle reduce.
__global__ __launch_bounds__(256) void readout(
    const int* __restrict__ tgt, const int* __restrict__ mnid,
    const unsigned short* __restrict__ featb, const float* __restrict__ p1mn,
    const float* __restrict__ base, float* __restrict__ acc,
    void* __restrict__ out, int last, float invNB, int BT,
    const int* __restrict__ dflag)
{
  int t = blockIdx.x*256 + threadIdx.x;
  int ti = t >> 4, l16 = t & 15;
  if (ti >= BT) return;
  int idx = tgt[ti]; int mn = mnid[idx];
  int h = l16 >> 1;
  float tw = base[h] + p1mn[(size_t)mn*HH + h];
  uint4 raw = *(const uint4*)(featb + (size_t)idx*DD + l16*8);
  const unsigned short* hw = (const unsigned short*)&raw;
  float s = 0.f;
#pragma unroll
  for (int j=0;j<8;j++) s += b2f(hw[j]);
  float part = tw * s;
  part += __shfl_xor(part, 1, 64);
  part += __shfl_xor(part, 2, 64);
  part += __shfl_xor(part, 4, 64);
  part += __shfl_xor(part, 8, 64);
  if (l16 == 0){
    if (!last) acc[ti] = part;
    else {
      float r = (acc[ti] + part) * invNB;
      if ((*dflag) != 0) ((float*)out)[ti] = r;
      else ((__hip_bfloat16*)out)[ti] = __float2bfloat16(r);
    }
  }
}

extern "C" void kernel_launch(void* const* d_in, const int* in_sizes, int n_in,
                              void* d_out, int out_size, void* d_ws, size_t ws_size,
                              hipStream_t stream) {
  const void* emb   = d_in[0];
  const void* u     = d_in[1];
  const void* W2lat = d_in[2];
  const void* W1lat = d_in[3];
  WPtrs wptrs;
  for (int i=0;i<8;i++) wptrs.p[i] = d_in[4+i];
  const int* node_vals      = (const int*)d_in[12];
  const int* meta_node_vals = (const int*)d_in[13];
  const int* src            = (const int*)d_in[14];
  const int* dst            = (const int*)d_in[15];
  const int* meta_src       = (const int*)d_in[16];
  const int* meta_dst       = (const int*)d_in[17];
  const int* meta_node_id   = (const int*)d_in[18];
  const int* meta_edge_id   = (const int*)d_in[19];
  const int* target_idx     = (const int*)d_in[20];
  const int* static_vals    = (const int*)d_in[21];
  const int* static_src     = (const int*)d_in[22];
  const int* static_dst     = (const int*)d_in[23];

  const int N  = in_sizes[12];
  const int MN = in_sizes[13];
  const int E  = in_sizes[14];
  const int ME = in_sizes[16];
  const int BT = in_sizes[20];
  const int NSRC = in_sizes[22];
  const int NB = in_sizes[8] / (DD*DD);

  float* ws = (float*)d_ws;
  size_t off = 0;
  auto allocf = [&](size_t n){ float* p = ws + off; off += n; return p; };
  auto allocb = [&](size_t n){ unsigned short* p = (unsigned short*)(ws + off); off += (n+1)/2; return p; };
  auto alloci = [&](size_t n){ int* p = (int*)(ws + off); off += n; return p; };
  int*            dflag = (int*)ws; off += 4;
  unsigned short* feat  = allocb((size_t)N*DD);
  unsigned short* q     = allocb((size_t)N*DD);
  unsigned char*  kv8   = (unsigned char*)allocf((size_t)N*64);  // N x 256B fp8 rows
  unsigned short* aggb  = allocb((size_t)N*DD);
  float*          z     = allocf((size_t)N*HH);
  float*          meta_feat= allocf((size_t)MN*DD);
  float*          agg_m = allocf((size_t)MN*DD);
  float*          z_m   = allocf((size_t)MN*HH);
  unsigned short* q_m   = allocb((size_t)MN*DD);
  unsigned short* kf_m  = allocb((size_t)MN*DD);
  unsigned short* v_m   = allocb((size_t)MN*DD);
  float*          p2mn  = allocf((size_t)MN*DD);
  float*          p1mn  = allocf((size_t)MN*HH);
  unsigned short* w2me  = allocb((size_t)ME*DD);
  unsigned short* p1me  = allocb((size_t)ME*HH);
  float*          base  = allocf(280);
  float*          acc   = allocf((size_t)BT);
  unsigned short* wstage= allocb((size_t)8*NB*DD*DD);
  int*            rowptr= alloci((size_t)N+1);
  int*            cursor= alloci((size_t)N);
  int*            epack = alloci((size_t)E);
  int*            rowptr_m= alloci((size_t)MN+1);
  int*            cursor_m= alloci((size_t)MN);
  int*            esrc_m  = alloci((size_t)ME);
  int*            eorig_m = alloci((size_t)ME);
  int*            degAll  = alloci((size_t)(N+MN));
  int*            deg     = degAll;
  int*            deg_m   = degAll + N;
  const int nb_scan   = (N + 1023)/1024;
  const int nb_scan_m = (MN + 1023)/1024;
  int*            bsum   = alloci((size_t)nb_scan);
  int*            bsum_m = alloci((size_t)nb_scan_m);
  (void)ws_size; (void)n_in; (void)out_size;

  const float* base_n2 = base + 24;

  k_detect<<<1,64,0,stream>>>((const unsigned short*)emb, dflag);
  k_static<<<1,256,0,stream>>>(emb, static_vals, static_src, static_dst,
                               u, W2lat, W1lat, base, NSRC, dflag);
  gather_rows2<<<((N+MN)*16+255)/256,256,0,stream>>>(emb, node_vals, feat, N,
      meta_node_vals, meta_feat, MN, dflag);

  const int nbE  = (E+255)/256, nbME = (ME+255)/256;
  const int nb3B = (N+255)/256, nb3M = (MN+255)/256;
  zeroi<<<(N+MN+255)/256,256,0,stream>>>(degAll, N+MN);
  k_hist2<<<nbE+nbME,256,0,stream>>>(dst, meta_dst, deg, deg_m, E, ME, nbE);
  k_scan1b<<<nb_scan+nb_scan_m,256,0,stream>>>(deg, rowptr, bsum, N, nb_scan,
      deg_m, rowptr_m, bsum_m, MN);
  k_scan3b<<<nb3B+nb3M,256,0,stream>>>(rowptr, bsum, cursor, N, nb3B, nb_scan,
      rowptr_m, bsum_m, cursor_m, MN, nb_scan_m);
  k_scatter2<<<nbE+nbME,256,0,stream>>>(dst, src, meta_edge_id, cursor,
      epack, E, nbE, meta_dst, meta_src, cursor_m, esrc_m, eorig_m, ME);

  w_repack16<<<8*NB*64,256,0,stream>>>(wptrs, wstage, NB, dflag);

  const int gm = (MN+63)/64;
  const int gN = (N+63)/64;
  const float invNB = 1.0f/(float)NB;

  for (int b=0;b<NB;b++){
    const unsigned short* wq_m = wstage + (size_t)(0*NB+b)*DD*DD;
    const unsigned short* wk_m = wstage + (size_t)(1*NB+b)*DD*DD;
    const unsigned short* wv_m = wstage + (size_t)(2*NB+b)*DD*DD;
    const unsigned short* wo_m = wstage + (size_t)(3*NB+b)*DD*DD;
    const unsigned short* wqb  = wstage + (size_t)(4*NB+b)*DD*DD;
    const unsigned short* wkb  = wstage + (size_t)(5*NB+b)*DD*DD;
    const unsigned short* wvb  = wstage + (size_t)(6*NB+b)*DD*DD;
    const unsigned short* wob  = wstage + (size_t)(7*NB+b)*DD*DD;

    // ---- meta conv (CSR, atomic-free; edge-learner fused) ----
    gemm_qkv<EPI_SCALE_CONST,false,false><<<gm,256,0,stream>>>(meta_feat,
        wq_m, wk_m, wv_m, q_m, kf_m, DD, v_m, DD, MN, base_n2, nullptr, nullptr);
    edge_meta_csr<<<(MN+3)/4,256,0,stream>>>(rowptr_m, esrc_m, eorig_m,
        q_m, kf_m, v_m, base, u, W2lat, W1lat, w2me, p1me, z_m, agg_m, MN, dflag);
    // meta Wo + residual + fused MN-learner
    gemm_wo_meta<<<gm,256,0,stream>>>(agg_m, wo_m, MN, z_m, meta_feat,
        u, W2lat, W1lat, p2mn, p1mn, dflag);

    // ---- big conv (fp8 kv) ----
    gemm_qkv<EPI_SCALE_GATHER,true,true><<<gN,256,0,stream>>>(feat, wqb, wkb, wvb,
        q, kv8, 0, kv8 + 128, 0, N, base_n2, p2mn, meta_node_id);
    edge_fused<<<(N+15)/16,256,0,stream>>>(rowptr, epack,
        meta_node_id, q, kv8, w2me, p1me, p1mn, base, z, aggb, N);
    gemm128m<EPI_RELU_RES,true,true,true><<<gN,256,0,stream>>>(aggb, wob, feat, N,
        z, nullptr, nullptr, nullptr, feat);

    // ---- readout ----
    readout<<<(BT*16+255)/256,256,0,stream>>>(target_idx, meta_node_id, feat, p1mn,
        base, acc, d_out, (b==NB-1) ? 1 : 0, invNB, BT, dflag);
  }
}

// Round 14
// 773.009 us; speedup vs baseline: 1.1879x; 1.1879x over previous
//
#include <hip/hip_runtime.h>
#include <hip/hip_bf16.h>
#include <hip/hip_fp8.h>

#define DD   128
#define HH   8

typedef short bf16x8 __attribute__((ext_vector_type(8)));
typedef float f32x4  __attribute__((ext_vector_type(4)));
typedef float f32x2  __attribute__((ext_vector_type(2)));

__device__ __forceinline__ float b2f(unsigned short v){
  union { unsigned int u; float f; } x; x.u = ((unsigned int)v) << 16; return x.f;
}
__device__ __forceinline__ unsigned short f2b(float f){
  __hip_bfloat16 h = __float2bfloat16(f);
  return *(unsigned short*)&h;
}
__device__ __forceinline__ unsigned char f2f8(float x){
  __hip_fp8_e4m3 h(x);
  return h.__x;
}
__device__ __forceinline__ float f82f(unsigned char b){
  __hip_fp8_e4m3 h; h.__x = b;
  return (float)h;
}
// 4 fp8 bytes (one u32) -> 4 floats; HW packed cvt when available.
__device__ __forceinline__ void cvt4(unsigned int w, float* o){
#if defined(__has_builtin)
# if __has_builtin(__builtin_amdgcn_cvt_pk_f32_fp8)
  f32x2 lo = __builtin_amdgcn_cvt_pk_f32_fp8((int)w, false);
  f32x2 hi = __builtin_amdgcn_cvt_pk_f32_fp8((int)w, true);
  o[0]=lo[0]; o[1]=lo[1]; o[2]=hi[0]; o[3]=hi[1];
  return;
# endif
#endif
  o[0]=f82f(w&0xff); o[1]=f82f((w>>8)&0xff);
  o[2]=f82f((w>>16)&0xff); o[3]=f82f((w>>24)&0xff);
}
struct __align__(8) us4 { unsigned short x,y,z,w; };

__device__ __forceinline__ float gld(const void* p, size_t i, bool f32){
  if (f32) return ((const float*)p)[i];
  return b2f(((const unsigned short*)p)[i]);
}

// Detect input float dtype. flag=1 -> inputs are f32.
__global__ __launch_bounds__(64) void k_detect(const unsigned short* __restrict__ emb,
                                               int* __restrict__ flag){
  int t = threadIdx.x;
  float m = 0.f;
  for (int i=t; i<128; i+=64){
    float x = fabsf(b2f(emb[i]));
    if (x < 1e30f) m = fmaxf(m, x);
  }
#pragma unroll
  for (int s=1;s<64;s<<=1) m = fmaxf(m, __shfl_xor(m, s, 64));
  if (t==0) *flag = (m > 1e4f) ? 1 : 0;
}

// ALL weight blocks (8 tensors x NB matrices) -> bf16 TRANSPOSED staging, one launch.
struct WPtrs { const void* p[8]; };
__global__ __launch_bounds__(256) void w_repack16(
    WPtrs W, unsigned short* __restrict__ stage, int NBt,
    const int* __restrict__ dflag)
{
  const bool wf32 = (*dflag) != 0;
  int idx = blockIdx.x >> 6;
  int ti = idx / NBt, bi = idx - ti*NBt;
  size_t bo = (size_t)bi*DD*DD;
  int i = (blockIdx.x & 63)*256 + threadIdx.x;
  int k = i >> 7, n = i & 127;
  float x;
  if (wf32) x = ((const float*)W.p[ti])[bo + i];
  else      x = b2f(((const unsigned short*)W.p[ti])[bo + i]);
  stage[(size_t)idx*DD*DD + n*DD + k] = f2b(x);
}

enum { EPI_STORE=0, EPI_SCALE_CONST=1, EPI_SCALE_GATHER=2, EPI_RELU=3,
       EPI_RELU_RES=4 };

#define APAD 136
#define CPAD 132

// C[M,128] = epi( prologue(A)[M,128] @ B[128,128] ), B bf16 TRANSPOSED ([n][k]).
template<int EPI, bool NORM, bool INB, bool OUTB>
__global__ __launch_bounds__(256) void gemm128m(
    const void* __restrict__ Av, const unsigned short* __restrict__ Bt,
    void* __restrict__ Cv, int M,
    const float* __restrict__ z, const float* __restrict__ svec,
    const float* __restrict__ P2, const int* __restrict__ gidx,
    const unsigned short* __restrict__ Rb)
{
  __shared__ unsigned short Asb[64*APAD];
  __shared__ unsigned short Btb[128*APAD];
  const int tid = threadIdx.x;
  const int wave = tid >> 6, lane = tid & 63;
  const int row0 = blockIdx.x * 64;

  {
    int r = tid >> 2, cb = (tid & 3) * 32;
    int gr = row0 + r;
    if (INB){
      const unsigned short* Ab = (const unsigned short*)Av;
#pragma unroll
      for (int j=0;j<4;j++){
        int c = cb + j*8;
        uint4 raw = make_uint4(0,0,0,0);
        if (gr < M) raw = *(const uint4*)(Ab + (size_t)gr*DD + c);
        if (NORM){
          float s = 0.f;
          if (gr < M) s = 1.0f/(z[(size_t)gr*HH + (c>>4)] + 1e-9f);
          const unsigned short* hw = (const unsigned short*)&raw;
          us4 o0, o1;
          o0.x=f2b(b2f(hw[0])*s); o0.y=f2b(b2f(hw[1])*s);
          o0.z=f2b(b2f(hw[2])*s); o0.w=f2b(b2f(hw[3])*s);
          o1.x=f2b(b2f(hw[4])*s); o1.y=f2b(b2f(hw[5])*s);
          o1.z=f2b(b2f(hw[6])*s); o1.w=f2b(b2f(hw[7])*s);
          *(us4*)&Asb[r*APAD + c] = o0; *(us4*)&Asb[r*APAD + c + 4] = o1;
        } else {
          *(uint4*)&Asb[r*APAD + c] = raw;
        }
      }
    } else {
      const float* Af = (const float*)Av;
#pragma unroll
      for (int j=0;j<8;j++){
        int c = cb + j*4;
        float4 val = make_float4(0.f,0.f,0.f,0.f);
        if (gr < M){
          val = *(const float4*)(Af + (size_t)gr*DD + c);
          if (NORM){
            float s = 1.0f / (z[(size_t)gr*HH + (c>>4)] + 1e-9f);
            val.x*=s; val.y*=s; val.z*=s; val.w*=s;
          }
        }
        us4 o; o.x=f2b(val.x); o.y=f2b(val.y); o.z=f2b(val.z); o.w=f2b(val.w);
        *(us4*)&Asb[r*APAD + c] = o;
      }
    }
  }
  {
    int n = tid >> 1, k0s = (tid & 1) * 64;
#pragma unroll
    for (int j=0;j<8;j++){
      uint4 raw = *(const uint4*)(Bt + (size_t)n*DD + k0s + j*8);
      *(uint4*)&Btb[n*APAD + k0s + j*8] = raw;
    }
  }
  __syncthreads();

  f32x4 acc[8];
#pragma unroll
  for (int t=0;t<8;t++) acc[t] = (f32x4){0.f,0.f,0.f,0.f};
  const int am = (lane & 15), kq = (lane >> 4) * 8;
#pragma unroll
  for (int k0=0;k0<128;k0+=32){
    bf16x8 a = *(bf16x8*)&Asb[(wave*16 + am)*APAD + k0 + kq];
#pragma unroll
    for (int t=0;t<8;t++){
      bf16x8 b = *(bf16x8*)&Btb[(t*16 + am)*APAD + k0 + kq];
      acc[t] = __builtin_amdgcn_mfma_f32_16x16x32_bf16(a, b, acc[t], 0,0,0);
    }
  }
  __syncthreads();
  float* Cls = (float*)Btb;
  {
    int rr = wave*16 + (lane>>4)*4;
    int cc = lane & 15;
#pragma unroll
    for (int t=0;t<8;t++)
#pragma unroll
      for (int r=0;r<4;r++)
        Cls[(rr + r)*CPAD + t*16 + cc] = acc[t][r];
  }
  __syncthreads();

  {
    int r = tid >> 2, cb = (tid & 3) * 32;
    int gr = row0 + r;
    if (gr < M){
#pragma unroll
      for (int j=0;j<8;j++){
        int c = cb + j*4;
        float4 o = *(float4*)&Cls[r*CPAD + c];
        if (EPI == EPI_SCALE_CONST){
          o.x*=svec[c+0]; o.y*=svec[c+1]; o.z*=svec[c+2]; o.w*=svec[c+3];
        } else if (EPI == EPI_SCALE_GATHER){
          int g = gidx[gr];
          const float* p = P2 + (size_t)g*DD + c;
          o.x*=(svec[c+0]+p[0]); o.y*=(svec[c+1]+p[1]);
          o.z*=(svec[c+2]+p[2]); o.w*=(svec[c+3]+p[3]);
        } else if (EPI == EPI_RELU){
          o.x=fmaxf(o.x,0.f); o.y=fmaxf(o.y,0.f); o.z=fmaxf(o.z,0.f); o.w=fmaxf(o.w,0.f);
        } else if (EPI == EPI_RELU_RES){
          us4 rb = *(const us4*)(Rb + (size_t)gr*DD + c);
          o.x=fmaxf(o.x,0.f)+b2f(rb.x); o.y=fmaxf(o.y,0.f)+b2f(rb.y);
          o.z=fmaxf(o.z,0.f)+b2f(rb.z); o.w=fmaxf(o.w,0.f)+b2f(rb.w);
        }
        if (OUTB){
          us4 ob; ob.x=f2b(o.x); ob.y=f2b(o.y); ob.z=f2b(o.z); ob.w=f2b(o.w);
          *(us4*)((unsigned short*)Cv + (size_t)gr*DD + c) = ob;
        } else {
          *(float4*)((float*)Cv + (size_t)gr*DD + c) = o;
        }
      }
    }
  }
}

// Meta Wo gemm + residual + FUSED MN-learner (wide-row parallel: OK to fuse).
__global__ __launch_bounds__(256) void gemm_wo_meta(
    const float* __restrict__ Af, const unsigned short* __restrict__ Bt, int M,
    const float* __restrict__ z, float* __restrict__ meta_feat,
    const void* __restrict__ u, const void* __restrict__ W2,
    const void* __restrict__ W1,
    float* __restrict__ p2mn, float* __restrict__ p1mn,
    const int* __restrict__ dflag)
{
  __shared__ unsigned short Asb[64*APAD];
  __shared__ unsigned short Btb[128*APAD];
  const bool wf32 = (*dflag) != 0;
  const int tid = threadIdx.x;
  const int wave = tid >> 6, lane = tid & 63;
  const int row0 = blockIdx.x * 64;

  {
    int r = tid >> 2, cb = (tid & 3) * 32;
    int gr = row0 + r;
#pragma unroll
    for (int j=0;j<8;j++){
      int c = cb + j*4;
      float4 val = make_float4(0.f,0.f,0.f,0.f);
      if (gr < M){
        val = *(const float4*)(Af + (size_t)gr*DD + c);
        float s = 1.0f / (z[(size_t)gr*HH + (c>>4)] + 1e-9f);
        val.x*=s; val.y*=s; val.z*=s; val.w*=s;
      }
      us4 o; o.x=f2b(val.x); o.y=f2b(val.y); o.z=f2b(val.z); o.w=f2b(val.w);
      *(us4*)&Asb[r*APAD + c] = o;
    }
  }
  {
    int n = tid >> 1, k0s = (tid & 1) * 64;
#pragma unroll
    for (int j=0;j<8;j++){
      uint4 raw = *(const uint4*)(Bt + (size_t)n*DD + k0s + j*8);
      *(uint4*)&Btb[n*APAD + k0s + j*8] = raw;
    }
  }
  __syncthreads();

  f32x4 acc[8];
#pragma unroll
  for (int t=0;t<8;t++) acc[t] = (f32x4){0.f,0.f,0.f,0.f};
  const int am = (lane & 15), kq = (lane >> 4) * 8;
#pragma unroll
  for (int k0=0;k0<128;k0+=32){
    bf16x8 a = *(bf16x8*)&Asb[(wave*16 + am)*APAD + k0 + kq];
#pragma unroll
    for (int t=0;t<8;t++){
      bf16x8 b = *(bf16x8*)&Btb[(t*16 + am)*APAD + k0 + kq];
      acc[t] = __builtin_amdgcn_mfma_f32_16x16x32_bf16(a, b, acc[t], 0,0,0);
    }
  }
  __syncthreads();
  float* Cls = (float*)Btb;
  {
    int rr = wave*16 + (lane>>4)*4;
    int cc = lane & 15;
#pragma unroll
    for (int t=0;t<8;t++)
#pragma unroll
      for (int r=0;r<4;r++)
        Cls[(rr + r)*CPAD + t*16 + cc] = acc[t][r];
  }
  __syncthreads();

  {
    int r = tid >> 2, cb = (tid & 3) * 32;
    int gr = row0 + r;
    float x[32];
    if (gr < M){
#pragma unroll
      for (int j=0;j<8;j++){
        int c = cb + j*4;
        float4 o = *(float4*)&Cls[r*CPAD + c];
        o.x=fmaxf(o.x,0.f); o.y=fmaxf(o.y,0.f); o.z=fmaxf(o.z,0.f); o.w=fmaxf(o.w,0.f);
        x[j*4+0]=o.x; x[j*4+1]=o.y; x[j*4+2]=o.z; x[j*4+3]=o.w;
        float4 rf = *(const float4*)(meta_feat + (size_t)gr*DD + c);
        *(float4*)(meta_feat + (size_t)gr*DD + c) =
            make_float4(o.x+rf.x, o.y+rf.y, o.z+rf.z, o.w+rf.w);
      }
      float swl[16]; float ssum = 0.f;
#pragma unroll
      for (int l=0;l<16;l++){
        float part = 0.f;
#pragma unroll
        for (int j=0;j<32;j++) part += x[j]*gld(u, l*128 + cb + j, wf32);
        part += __shfl_xor(part, 1, 64);
        part += __shfl_xor(part, 2, 64);
        float e = __expf(part * 0.08838834764831845f);
        swl[l] = e; ssum += e;
      }
      float inv = 1.f/ssum;
#pragma unroll
      for (int j=0;j<32;j++){
        float a = 0.f;
#pragma unroll
        for (int l=0;l<16;l++) a += swl[l]*gld(W2, l*128 + cb + j, wf32);
        p2mn[(size_t)gr*DD + cb + j] = a*inv;
      }
      if ((tid & 3) == 0){
#pragma unroll
        for (int h=0;h<8;h++){
          float a = 0.f;
#pragma unroll
          for (int l=0;l<16;l++) a += swl[l]*gld(W1, l*8 + h, wf32);
          p1mn[(size_t)gr*HH + h] = a*inv;
        }
      }
    }
  }
}

// Fused Q/K/V gemm. FP8KV: phases 1/2 write fp8 (x8 scale) into 256B/row kv buffer.
template<int EPIQ, bool INB, bool FP8KV>
__global__ __launch_bounds__(256) void gemm_qkv(
    const void* __restrict__ Av,
    const unsigned short* __restrict__ Btq, const unsigned short* __restrict__ Btk,
    const unsigned short* __restrict__ Btv,
    void* __restrict__ Cq, void* __restrict__ Ck, int stK,
    void* __restrict__ Cvo, int stV, int M,
    const float* __restrict__ svec, const float* __restrict__ P2,
    const int* __restrict__ gidx)
{
  __shared__ unsigned short Asb[64*APAD];
  __shared__ unsigned short Btb[128*APAD];
  const int tid = threadIdx.x;
  const int wave = tid >> 6, lane = tid & 63;
  const int row0 = blockIdx.x * 64;

  {
    int r = tid >> 2, cb = (tid & 3) * 32;
    int gr = row0 + r;
    if (INB){
      const unsigned short* Ab = (const unsigned short*)Av;
#pragma unroll
      for (int j=0;j<4;j++){
        int c = cb + j*8;
        uint4 raw = make_uint4(0,0,0,0);
        if (gr < M) raw = *(const uint4*)(Ab + (size_t)gr*DD + c);
        *(uint4*)&Asb[r*APAD + c] = raw;
      }
    } else {
      const float* Af = (const float*)Av;
#pragma unroll
      for (int j=0;j<8;j++){
        int c = cb + j*4;
        float4 val = make_float4(0.f,0.f,0.f,0.f);
        if (gr < M) val = *(const float4*)(Af + (size_t)gr*DD + c);
        us4 o; o.x=f2b(val.x); o.y=f2b(val.y); o.z=f2b(val.z); o.w=f2b(val.w);
        *(us4*)&Asb[r*APAD + c] = o;
      }
    }
  }

  const unsigned short* Bts[3] = {Btq, Btk, Btv};
  void* Cs[3] = {Cq, Ck, Cvo};
  const int sts[3] = {DD, stK, stV};
  const int am = (lane & 15), kq = (lane >> 4) * 8;

  for (int ph=0; ph<3; ph++){
    {
      int n = tid >> 1, k0s = (tid & 1) * 64;
      const unsigned short* Bt = Bts[ph];
#pragma unroll
      for (int j=0;j<8;j++){
        uint4 raw = *(const uint4*)(Bt + (size_t)n*DD + k0s + j*8);
        *(uint4*)&Btb[n*APAD + k0s + j*8] = raw;
      }
    }
    __syncthreads();
    f32x4 acc[8];
#pragma unroll
    for (int t=0;t<8;t++) acc[t] = (f32x4){0.f,0.f,0.f,0.f};
#pragma unroll
    for (int k0=0;k0<128;k0+=32){
      bf16x8 a = *(bf16x8*)&Asb[(wave*16 + am)*APAD + k0 + kq];
#pragma unroll
      for (int t=0;t<8;t++){
        bf16x8 b = *(bf16x8*)&Btb[(t*16 + am)*APAD + k0 + kq];
        acc[t] = __builtin_amdgcn_mfma_f32_16x16x32_bf16(a, b, acc[t], 0,0,0);
      }
    }
    __syncthreads();
    float* Cls = (float*)Btb;
    {
      int rr = wave*16 + (lane>>4)*4;
      int cc = lane & 15;
#pragma unroll
      for (int t=0;t<8;t++)
#pragma unroll
        for (int r=0;r<4;r++)
          Cls[(rr + r)*CPAD + t*16 + cc] = acc[t][r];
    }
    __syncthreads();
    {
      int r = tid >> 2, cb = (tid & 3) * 32;
      int gr = row0 + r;
      if (gr < M){
#pragma unroll
        for (int j=0;j<8;j++){
          int c = cb + j*4;
          float4 o = *(float4*)&Cls[r*CPAD + c];
          if (ph == 0){
            if (EPIQ == EPI_SCALE_GATHER){
              int g = gidx[gr];
              const float* p = P2 + (size_t)g*DD + c;
              o.x*=(svec[c+0]+p[0]); o.y*=(svec[c+1]+p[1]);
              o.z*=(svec[c+2]+p[2]); o.w*=(svec[c+3]+p[3]);
            } else {
              o.x*=svec[c+0]; o.y*=svec[c+1]; o.z*=svec[c+2]; o.w*=svec[c+3];
            }
          }
          if (FP8KV && ph > 0){
            unsigned char* Cb = (unsigned char*)Cs[ph];
            uchar4 ob;
            ob.x=f2f8(o.x*8.f); ob.y=f2f8(o.y*8.f);
            ob.z=f2f8(o.z*8.f); ob.w=f2f8(o.w*8.f);
            *(uchar4*)(Cb + (size_t)gr*256 + c) = ob;
          } else {
            us4 ob; ob.x=f2b(o.x); ob.y=f2b(o.y); ob.z=f2b(o.z); ob.w=f2b(o.w);
            *(us4*)((unsigned short*)Cs[ph] + (size_t)gr*sts[ph] + c) = ob;
          }
        }
      }
    }
    __syncthreads();
  }
}

// Static param-name graph -> base params.
__global__ __launch_bounds__(256) void k_static(
    const void* __restrict__ emb, const int* __restrict__ svals,
    const int* __restrict__ ssrc, const int* __restrict__ sdst,
    const void* __restrict__ u, const void* __restrict__ W2,
    const void* __restrict__ W1, float* __restrict__ base, int nsrc,
    const int* __restrict__ dflag)
{
  __shared__ float sagg[15][128];
  __shared__ float ssc[15][16];
  __shared__ float sww[15][16];
  const bool wf32 = (*dflag) != 0;
  const int t = threadIdx.x;
  for (int i=t;i<15*128;i+=256) ((float*)sagg)[i]=0.f;
  __syncthreads();
  if (t < 128){
    for (int i=0;i<nsrc;i++){
      int row = sdst[i]; int vr = svals[ssrc[i]];
      sagg[row][t] += gld(emb, (size_t)vr*DD + t, wf32);
    }
  }
  __syncthreads();
  if (t < 240){
    int n = t>>4, l = t&15;
    float a=0.f;
    for (int d=0;d<128;d++) a += sagg[n][d]*gld(u, l*128+d, wf32);
    ssc[n][l] = a * 0.08838834764831845f;
  }
  __syncthreads();
  if (t < 15){
    float mx=-1e30f;
    for (int l=0;l<16;l++) mx = fmaxf(mx, ssc[t][l]);
    float s=0.f;
    for (int l=0;l<16;l++){ float e=__expf(ssc[t][l]-mx); sww[t][l]=e; s+=e; }
    float inv = 1.f/s;
    for (int l=0;l<16;l++) sww[t][l]*=inv;
  }
  __syncthreads();
  if (t < 8){
    float a=0.f,b=0.f,c=0.f;
    for (int l=0;l<16;l++){
      float wv = gld(W1, l*8+t, wf32);
      a += sww[0][l]*wv; b += sww[3][l]*wv; c += sww[9][l]*wv;
    }
    base[t]=a; base[8+t]=b; base[16+t]=c;
  }
  if (t < 128){
    float a=0.f,b=0.f;
    for (int l=0;l<16;l++){
      float wv = gld(W2, l*128+t, wf32);
      a += sww[6][l]*wv; b += sww[12][l]*wv;
    }
    base[24+t]=a; base[152+t]=b;
  }
}

// Merged gather: big graph rows -> bf16 feat; meta rows -> f32 meta_feat.
__global__ __launch_bounds__(256) void gather_rows2(
    const void* __restrict__ emb,
    const int* __restrict__ valsB, unsigned short* __restrict__ featB, int nB,
    const int* __restrict__ valsM, float* __restrict__ featM, int nM,
    const int* __restrict__ dflag)
{
  const bool wf32 = (*dflag) != 0;
  int i = blockIdx.x*256 + threadIdx.x;
  bool big = (i < nB*16);
  int i2 = big ? i : (i - nB*16);
  if (!big && i2 >= nM*16) return;
  int r = i2>>4, c = (i2&15)*8;
  int vr = big ? valsB[r] : valsM[r];
  float vb[8];
  if (wf32){
    float4 f0 = *(const float4*)((const float*)emb + (size_t)vr*DD + c);
    float4 f1 = *(const float4*)((const float*)emb + (size_t)vr*DD + c + 4);
    vb[0]=f0.x; vb[1]=f0.y; vb[2]=f0.z; vb[3]=f0.w;
    vb[4]=f1.x; vb[5]=f1.y; vb[6]=f1.z; vb[7]=f1.w;
  } else {
    uint4 raw = *(const uint4*)((const unsigned short*)emb + (size_t)vr*DD + c);
    const unsigned short* hw = (const unsigned short*)&raw;
#pragma unroll
    for (int j=0;j<8;j++) vb[j] = b2f(hw[j]);
  }
  if (big){
    unsigned short* d = featB + (size_t)r*DD + c;
    us4 o0, o1;
    o0.x=f2b(vb[0]); o0.y=f2b(vb[1]); o0.z=f2b(vb[2]); o0.w=f2b(vb[3]);
    o1.x=f2b(vb[4]); o1.y=f2b(vb[5]); o1.z=f2b(vb[6]); o1.w=f2b(vb[7]);
    *(us4*)d = o0; *(us4*)(d+4) = o1;
  } else {
    float* d = featM + (size_t)r*DD + c;
    *(float4*)d     = make_float4(vb[0],vb[1],vb[2],vb[3]);
    *(float4*)(d+4) = make_float4(vb[4],vb[5],vb[6],vb[7]);
  }
}

__global__ __launch_bounds__(256) void zeroi(int* __restrict__ p, int n){
  int i = blockIdx.x*256 + threadIdx.x;
  if (i < n) p[i] = 0;
}

// ---------------- merged CSR build (big + meta graphs) ----------------
__global__ __launch_bounds__(256) void k_hist2(
    const int* __restrict__ dstB, const int* __restrict__ dstM,
    int* __restrict__ degB, int* __restrict__ degM, int E, int ME, int nbE){
  int b = blockIdx.x, t = threadIdx.x;
  if (b < nbE){ int i = b*256+t; if (i < E) atomicAdd(&degB[dstB[i]], 1); }
  else { int i = (b-nbE)*256+t; if (i < ME) atomicAdd(&degM[dstM[i]], 1); }
}

__global__ __launch_bounds__(256) void k_scan1b(
    const int* __restrict__ degB, int* __restrict__ rpB, int* __restrict__ bsB,
    int nB, int nbB,
    const int* __restrict__ degM, int* __restrict__ rpM, int* __restrict__ bsM,
    int nM){
  __shared__ int ls[256];
  int blk = blockIdx.x, t = threadIdx.x;
  const int* deg; int* rowptr; int* bsum; int n; int b;
  if (blk < nbB){ deg=degB; rowptr=rpB; bsum=bsB; n=nB; b=blk; }
  else          { deg=degM; rowptr=rpM; bsum=bsM; n=nM; b=blk-nbB; }
  int base = b*1024 + t*4;
  int v0 = (base+0<n)?deg[base+0]:0;
  int v1 = (base+1<n)?deg[base+1]:0;
  int v2 = (base+2<n)?deg[base+2]:0;
  int v3 = (base+3<n)?deg[base+3]:0;
  int tsum = v0+v1+v2+v3;
  ls[t] = tsum; __syncthreads();
  for (int o=1;o<256;o<<=1){
    int x = (t>=o) ? ls[t-o] : 0;
    __syncthreads();
    ls[t] += x;
    __syncthreads();
  }
  int excl = ls[t]-tsum;
  if (t==255) bsum[b] = ls[255];
  if (base+0<n) rowptr[base+0]=excl;
  if (base+1<n) rowptr[base+1]=excl+v0;
  if (base+2<n) rowptr[base+2]=excl+v0+v1;
  if (base+3<n) rowptr[base+3]=excl+v0+v1+v2;
}

// scan3 with in-block prefix of block sums (scan2 merged in).
__global__ __launch_bounds__(256) void k_scan3b(
    int* __restrict__ rpB, const int* __restrict__ bsB, int* __restrict__ curB,
    int nB, int nb3B, int nbsB,
    int* __restrict__ rpM, const int* __restrict__ bsM, int* __restrict__ curM,
    int nM, int nbsM){
  __shared__ int spre;
  int blk = blockIdx.x, t = threadIdx.x;
  if (blk < nb3B){
    if (t == 0){
      int chunk = blk >> 2;
      int pre = 0;
      for (int j=0;j<chunk;j++) pre += bsB[j];
      spre = pre;
      if (blk == 0){
        int tot = 0;
        for (int j=0;j<nbsB;j++) tot += bsB[j];
        rpB[nB] = tot;
      }
    }
    __syncthreads();
    int i = blk*256 + t;
    if (i < nB){ int r = rpB[i] + spre; rpB[i] = r; curB[i] = r; }
  } else {
    int b2 = blk - nb3B;
    if (t == 0){
      int chunk = b2 >> 2;
      int pre = 0;
      for (int j=0;j<chunk;j++) pre += bsM[j];
      spre = pre;
      if (b2 == 0){
        int tot = 0;
        for (int j=0;j<nbsM;j++) tot += bsM[j];
        rpM[nM] = tot;
      }
    }
    __syncthreads();
    int i = b2*256 + t;
    if (i < nM){ int r = rpM[i] + spre; rpM[i] = r; curM[i] = r; }
  }
}

// scatter. Big graph: pack (src | meid<<17) into one int.
__global__ __launch_bounds__(256) void k_scatter2(
    const int* __restrict__ dstB, const int* __restrict__ srcB,
    const int* __restrict__ auxB, int* __restrict__ curB,
    int* __restrict__ epackB, int E, int nbE,
    const int* __restrict__ dstM, const int* __restrict__ srcM,
    int* __restrict__ curM, int* __restrict__ esrcM, int* __restrict__ eauxM,
    int ME){
  int blk = blockIdx.x, t = threadIdx.x;
  if (blk < nbE){
    int e = blk*256 + t;
    if (e < E){
      int p = atomicAdd(&curB[dstB[e]], 1);
      epackB[p] = srcB[e] | (auxB[e] << 17);
    }
  } else {
    int e = (blk-nbE)*256 + t;
    if (e < ME){
      int p = atomicAdd(&curM[dstM[e]], 1);
      esrcM[p] = srcM[e];
      eauxM[p] = e;
    }
  }
}

// ---------------- meta-graph edges: CSR, atomic-free, writes mef ----------------
__global__ __launch_bounds__(256) void edge_meta_csr(
    const int* __restrict__ rowptr, const int* __restrict__ esrc,
    const int* __restrict__ eorig,
    const unsigned short* __restrict__ qm, const unsigned short* __restrict__ kfm,
    const unsigned short* __restrict__ vm,
    const float* __restrict__ base, unsigned short* __restrict__ mef,
    float* __restrict__ z, float* __restrict__ agg, int NM)
{
  int d = blockIdx.x*4 + (threadIdx.x>>6);
  if (d >= NM) return;
  int lane = threadIdx.x & 63;
  const float* be2 = base+152; const float* be1 = base+16; const float* bn1 = base+8;
  size_t dq = (size_t)d*DD;
  float q0 = b2f(qm[dq+lane]), q1 = b2f(qm[dq+64+lane]);
  float w0 = be2[lane], w1 = be2[64+lane];
  int h0 = lane>>4, h1 = h0+4;
  float bias0 = be1[h0] + bn1[h0];
  float bias1 = be1[h1] + bn1[h1];
  float z0=0.f, z1=0.f, a0=0.f, a1=0.f;
  int i0 = rowptr[d], i1 = rowptr[d+1];
  for (int i=i0; i<i1; i++){
    int s = esrc[i], e = eorig[i];
    size_t so=(size_t)s*DD, eo=(size_t)e*DD;
    float ke0 = b2f(kfm[so+lane])    * w0;
    float ke1 = b2f(kfm[so+64+lane]) * w1;
    mef[eo+lane]=f2b(ke0); mef[eo+64+lane]=f2b(ke1);
    float p0 = q0*ke0, p1 = q1*ke1;
#pragma unroll
    for (int m=1;m<16;m<<=1){ p0 += __shfl_xor(p0,m,64); p1 += __shfl_xor(p1,m,64); }
    float e0 = __expf(p0*0.25f + bias0);
    float e1 = __expf(p1*0.25f + bias1);
    z0 += e0; z1 += e1;
    a0 += e0*b2f(vm[so+lane]);
    a1 += e1*b2f(vm[so+64+lane]);
  }
  if ((lane&15)==0){ z[(size_t)d*HH+h0] = z0; z[(size_t)d*HH+h1] = z1; }
  agg[dq+lane]    = a0;
  agg[dq+64+lane] = a1;
}

// ME-learner: one block per meta-edge (8000-way parallel — do NOT fuse into
// the 250-wave edge_meta_csr; round-13 showed that serializes catastrophically).
__global__ __launch_bounds__(128) void learner_me(
    const unsigned short* __restrict__ Xb,
    const void* __restrict__ u, const void* __restrict__ W2,
    const void* __restrict__ W1,
    unsigned short* __restrict__ w2me, unsigned short* __restrict__ p1b,
    const float* __restrict__ base, const int* __restrict__ dflag)
{
  __shared__ float sX[128];
  __shared__ float st[16];
  __shared__ float sw[16];
  const bool wf32 = (*dflag) != 0;
  const int m = blockIdx.x, t = threadIdx.x;
  sX[t] = b2f(Xb[(size_t)m*DD + t]);
  __syncthreads();
  int l = t>>3, j = t&7;
  float part = 0.f;
  for (int d=j*16; d<j*16+16; d++) part += sX[d]*gld(u, l*128+d, wf32);
  part += __shfl_xor(part,1,64); part += __shfl_xor(part,2,64); part += __shfl_xor(part,4,64);
  if (j==0) st[l] = part * 0.08838834764831845f;
  __syncthreads();
  float mx=-1e30f;
  for (int i=0;i<16;i++) mx = fmaxf(mx, st[i]);
  float ssum=0.f;
  for (int i=0;i<16;i++) ssum += __expf(st[i]-mx);
  float inv = 1.f/ssum;
  if (t<16) sw[t] = __expf(st[t]-mx)*inv;
  __syncthreads();
  float a=0.f;
  for (int i=0;i<16;i++) a += sw[i]*gld(W2, i*128+t, wf32);
  w2me[(size_t)m*DD+t] = f2b(base[152+t] + a);
  if (t<8){
    float bb=0.f;
    for (int i=0;i<16;i++) bb += sw[i]*gld(W1, i*8+t, wf32);
    p1b[(size_t)m*HH+t] = f2b(bb);
  }
}

// ---------------- big-graph: fused scores+agg, fp8 kv, packed indices ----------
__global__ __launch_bounds__(256) void edge_fused(
    const int* __restrict__ rowptr, const int* __restrict__ epack,
    const int* __restrict__ mnid,
    const unsigned short* __restrict__ q, const unsigned char* __restrict__ kv8,
    const unsigned short* __restrict__ w2me, const unsigned short* __restrict__ p1me,
    const float* __restrict__ p1mn, const float* __restrict__ base,
    float* __restrict__ z, unsigned short* __restrict__ aggb, int N)
{
  int wv = blockIdx.x*4 + (threadIdx.x>>6);
  int d0 = wv*4;
  if (d0 >= N) return;
  int lane = threadIdx.x & 63;
  int grp = lane >> 4, l16 = lane & 15;
  int c8 = l16 * 8;
  int h = l16 >> 1;
  const float* be1 = base+16; const float* bn1 = base+8;
  const float biash = be1[h] + bn1[h];

  for (int dd=0; dd<4; dd++){
    int d = d0 + dd;
    if (d >= N) break;
    size_t dq = (size_t)d*DD;
    float qv[8];
    {
      uint4 qraw = *(const uint4*)(q + dq + c8);
      const unsigned short* qh = (const unsigned short*)&qraw;
#pragma unroll
      for (int j=0;j<8;j++) qv[j] = b2f(qh[j])*0.03125f;  // 0.25 * 1/8 (k fp8 scale)
    }
    int mn = mnid[d];
    float bias = biash + p1mn[(size_t)mn*HH + h];

    float zh = 0.f;
    float a[8];
#pragma unroll
    for (int j=0;j<8;j++) a[j] = 0.f;

    int i0 = rowptr[d], i1 = rowptr[d+1];
    int i = i0 + grp;
    for (; i + 4 < i1; i += 8){
      unsigned int v0p = (unsigned int)epack[i];
      unsigned int v1p = (unsigned int)epack[i+4];
      int s0 = v0p & 0x1FFFF, me0 = v0p >> 17;
      int s1 = v1p & 0x1FFFF, me1 = v1p >> 17;
      size_t kvo0 = (size_t)s0*256, mo0 = (size_t)me0*DD;
      size_t kvo1 = (size_t)s1*256, mo1 = (size_t)me1*DD;
      uint2 kraw0 = *(const uint2*)(kv8 + kvo0 + c8);
      uint2 vraw0 = *(const uint2*)(kv8 + kvo0 + 128 + c8);
      uint4 wraw0 = *(const uint4*)(w2me + mo0 + c8);
      float pm0 = b2f(p1me[(size_t)me0*HH + h]);
      uint2 kraw1 = *(const uint2*)(kv8 + kvo1 + c8);
      uint2 vraw1 = *(const uint2*)(kv8 + kvo1 + 128 + c8);
      uint4 wraw1 = *(const uint4*)(w2me + mo1 + c8);
      float pm1 = b2f(p1me[(size_t)me1*HH + h]);
      float k0f[8], v0f[8], k1f[8], v1f[8];
      cvt4(kraw0.x, k0f); cvt4(kraw0.y, k0f+4);
      cvt4(vraw0.x, v0f); cvt4(vraw0.y, v0f+4);
      cvt4(kraw1.x, k1f); cvt4(kraw1.y, k1f+4);
      cvt4(vraw1.x, v1f); cvt4(vraw1.y, v1f+4);
      const unsigned short* wh0 = (const unsigned short*)&wraw0;
      const unsigned short* wh1 = (const unsigned short*)&wraw1;
      float pA = 0.f, pB = 0.f;
#pragma unroll
      for (int j=0;j<8;j++){
        pA += qv[j]*(k0f[j]*b2f(wh0[j]));
        pB += qv[j]*(k1f[j]*b2f(wh1[j]));
      }
      pA += __shfl_xor(pA, 1, 64);
      pB += __shfl_xor(pB, 1, 64);
      float ex0 = __expf(pA + bias + pm0);
      float ex1 = __expf(pB + bias + pm1);
      zh += ex0 + ex1;
      float ev0 = ex0*0.125f, ev1 = ex1*0.125f;
#pragma unroll
      for (int j=0;j<8;j++) a[j] += ev0*v0f[j] + ev1*v1f[j];
    }
    if (i < i1){
      unsigned int vp = (unsigned int)epack[i];
      int s = vp & 0x1FFFF, me = vp >> 17;
      size_t kvo = (size_t)s*256, mo = (size_t)me*DD;
      uint2 kraw = *(const uint2*)(kv8 + kvo + c8);
      uint2 vraw = *(const uint2*)(kv8 + kvo + 128 + c8);
      uint4 wraw = *(const uint4*)(w2me + mo + c8);
      float pm = b2f(p1me[(size_t)me*HH + h]);
      float kf[8], vf[8];
      cvt4(kraw.x, kf); cvt4(kraw.y, kf+4);
      cvt4(vraw.x, vf); cvt4(vraw.y, vf+4);
      const unsigned short* wh = (const unsigned short*)&wraw;
      float p = 0.f;
#pragma unroll
      for (int j=0;j<8;j++) p += qv[j]*(kf[j]*b2f(wh[j]));
      p += __shfl_xor(p, 1, 64);
      float ex = __expf(p + bias + pm);
      zh += ex;
      float ev = ex*0.125f;
#pragma unroll
      for (int j=0;j<8;j++) a[j] += ev*vf[j];
    }

    zh += __shfl_xor(zh, 16, 64); zh += __shfl_xor(zh, 32, 64);
#pragma unroll
    for (int j=0;j<8;j++){
      a[j] += __shfl_xor(a[j], 16, 64);
      a[j] += __shfl_xor(a[j], 32, 64);
    }
    if (grp == 0){
      us4 o0, o1;
      o0.x=f2b(a[0]); o0.y=f2b(a[1]); o0.z=f2b(a[2]); o0.w=f2b(a[3]);
      o1.x=f2b(a[4]); o1.y=f2b(a[5]); o1.z=f2b(a[6]); o1.w=f2b(a[7]);
      *(us4*)(aggb + dq + c8)     = o0;
      *(us4*)(aggb + dq + c8 + 4) = o1;
      if ((l16 & 1) == 0) z[(size_t)d*HH + h] = zh;
    }
  }
}

// One 16-lane group per target; vectorized feat row read + shuffle reduce.
__global__ __launch_bounds__(256) void readout(
    const int* __restrict__ tgt, const int* __restrict__ mnid,
    const unsigned short* __restrict__ featb, const float* __restrict__ p1mn,
    const float* __restrict__ base, float* __restrict__ acc,
    void* __restrict__ out, int last, float invNB, int BT,
    const int* __restrict__ dflag)
{
  int t = blockIdx.x*256 + threadIdx.x;
  int ti = t >> 4, l16 = t & 15;
  if (ti >= BT) return;
  int idx = tgt[ti]; int mn = mnid[idx];
  int h = l16 >> 1;
  float tw = base[h] + p1mn[(size_t)mn*HH + h];
  uint4 raw = *(const uint4*)(featb + (size_t)idx*DD + l16*8);
  const unsigned short* hw = (const unsigned short*)&raw;
  float s = 0.f;
#pragma unroll
  for (int j=0;j<8;j++) s += b2f(hw[j]);
  float part = tw * s;
  part += __shfl_xor(part, 1, 64);
  part += __shfl_xor(part, 2, 64);
  part += __shfl_xor(part, 4, 64);
  part += __shfl_xor(part, 8, 64);
  if (l16 == 0){
    if (!last) acc[ti] = part;
    else {
      float r = (acc[ti] + part) * invNB;
      if ((*dflag) != 0) ((float*)out)[ti] = r;
      else ((__hip_bfloat16*)out)[ti] = __float2bfloat16(r);
    }
  }
}

extern "C" void kernel_launch(void* const* d_in, const int* in_sizes, int n_in,
                              void* d_out, int out_size, void* d_ws, size_t ws_size,
                              hipStream_t stream) {
  const void* emb   = d_in[0];
  const void* u     = d_in[1];
  const void* W2lat = d_in[2];
  const void* W1lat = d_in[3];
  WPtrs wptrs;
  for (int i=0;i<8;i++) wptrs.p[i] = d_in[4+i];
  const int* node_vals      = (const int*)d_in[12];
  const int* meta_node_vals = (const int*)d_in[13];
  const int* src            = (const int*)d_in[14];
  const int* dst            = (const int*)d_in[15];
  const int* meta_src       = (const int*)d_in[16];
  const int* meta_dst       = (const int*)d_in[17];
  const int* meta_node_id   = (const int*)d_in[18];
  const int* meta_edge_id   = (const int*)d_in[19];
  const int* target_idx     = (const int*)d_in[20];
  const int* static_vals    = (const int*)d_in[21];
  const int* static_src     = (const int*)d_in[22];
  const int* static_dst     = (const int*)d_in[23];

  const int N  = in_sizes[12];
  const int MN = in_sizes[13];
  const int E  = in_sizes[14];
  const int ME = in_sizes[16];
  const int BT = in_sizes[20];
  const int NSRC = in_sizes[22];
  const int NB = in_sizes[8] / (DD*DD);

  float* ws = (float*)d_ws;
  size_t off = 0;
  auto allocf = [&](size_t n){ float* p = ws + off; off += n; return p; };
  auto allocb = [&](size_t n){ unsigned short* p = (unsigned short*)(ws + off); off += (n+1)/2; return p; };
  auto alloci = [&](size_t n){ int* p = (int*)(ws + off); off += n; return p; };
  int*            dflag = (int*)ws; off += 4;
  unsigned short* feat  = allocb((size_t)N*DD);
  unsigned short* q     = allocb((size_t)N*DD);
  unsigned char*  kv8   = (unsigned char*)allocf((size_t)N*64);  // N x 256B fp8 rows
  unsigned short* aggb  = allocb((size_t)N*DD);
  float*          z     = allocf((size_t)N*HH);
  float*          meta_feat= allocf((size_t)MN*DD);
  float*          agg_m = allocf((size_t)MN*DD);
  float*          z_m   = allocf((size_t)MN*HH);
  unsigned short* q_m   = allocb((size_t)MN*DD);
  unsigned short* kf_m  = allocb((size_t)MN*DD);
  unsigned short* v_m   = allocb((size_t)MN*DD);
  unsigned short* mef   = allocb((size_t)ME*DD);
  float*          p2mn  = allocf((size_t)MN*DD);
  float*          p1mn  = allocf((size_t)MN*HH);
  unsigned short* w2me  = allocb((size_t)ME*DD);
  unsigned short* p1me  = allocb((size_t)ME*HH);
  float*          base  = allocf(280);
  float*          acc   = allocf((size_t)BT);
  unsigned short* wstage= allocb((size_t)8*NB*DD*DD);
  int*            rowptr= alloci((size_t)N+1);
  int*            cursor= alloci((size_t)N);
  int*            epack = alloci((size_t)E);
  int*            rowptr_m= alloci((size_t)MN+1);
  int*            cursor_m= alloci((size_t)MN);
  int*            esrc_m  = alloci((size_t)ME);
  int*            eorig_m = alloci((size_t)ME);
  int*            degAll  = alloci((size_t)(N+MN));
  int*            deg     = degAll;
  int*            deg_m   = degAll + N;
  const int nb_scan   = (N + 1023)/1024;
  const int nb_scan_m = (MN + 1023)/1024;
  int*            bsum   = alloci((size_t)nb_scan);
  int*            bsum_m = alloci((size_t)nb_scan_m);
  (void)ws_size; (void)n_in; (void)out_size;

  const float* base_n2 = base + 24;

  k_detect<<<1,64,0,stream>>>((const unsigned short*)emb, dflag);
  k_static<<<1,256,0,stream>>>(emb, static_vals, static_src, static_dst,
                               u, W2lat, W1lat, base, NSRC, dflag);
  gather_rows2<<<((N+MN)*16+255)/256,256,0,stream>>>(emb, node_vals, feat, N,
      meta_node_vals, meta_feat, MN, dflag);

  const int nbE  = (E+255)/256, nbME = (ME+255)/256;
  const int nb3B = (N+255)/256, nb3M = (MN+255)/256;
  zeroi<<<(N+MN+255)/256,256,0,stream>>>(degAll, N+MN);
  k_hist2<<<nbE+nbME,256,0,stream>>>(dst, meta_dst, deg, deg_m, E, ME, nbE);
  k_scan1b<<<nb_scan+nb_scan_m,256,0,stream>>>(deg, rowptr, bsum, N, nb_scan,
      deg_m, rowptr_m, bsum_m, MN);
  k_scan3b<<<nb3B+nb3M,256,0,stream>>>(rowptr, bsum, cursor, N, nb3B, nb_scan,
      rowptr_m, bsum_m, cursor_m, MN, nb_scan_m);
  k_scatter2<<<nbE+nbME,256,0,stream>>>(dst, src, meta_edge_id, cursor,
      epack, E, nbE, meta_dst, meta_src, cursor_m, esrc_m, eorig_m, ME);

  w_repack16<<<8*NB*64,256,0,stream>>>(wptrs, wstage, NB, dflag);

  const int gm = (MN+63)/64;
  const int gN = (N+63)/64;
  const float invNB = 1.0f/(float)NB;

  for (int b=0;b<NB;b++){
    const unsigned short* wq_m = wstage + (size_t)(0*NB+b)*DD*DD;
    const unsigned short* wk_m = wstage + (size_t)(1*NB+b)*DD*DD;
    const unsigned short* wv_m = wstage + (size_t)(2*NB+b)*DD*DD;
    const unsigned short* wo_m = wstage + (size_t)(3*NB+b)*DD*DD;
    const unsigned short* wqb  = wstage + (size_t)(4*NB+b)*DD*DD;
    const unsigned short* wkb  = wstage + (size_t)(5*NB+b)*DD*DD;
    const unsigned short* wvb  = wstage + (size_t)(6*NB+b)*DD*DD;
    const unsigned short* wob  = wstage + (size_t)(7*NB+b)*DD*DD;

    // ---- meta conv (CSR, atomic-free) ----
    gemm_qkv<EPI_SCALE_CONST,false,false><<<gm,256,0,stream>>>(meta_feat,
        wq_m, wk_m, wv_m, q_m, kf_m, DD, v_m, DD, MN, base_n2, nullptr, nullptr);
    edge_meta_csr<<<(MN+3)/4,256,0,stream>>>(rowptr_m, esrc_m, eorig_m,
        q_m, kf_m, v_m, base, mef, z_m, agg_m, MN);
    // ME-learner on mef (wide-parallel separate kernel)
    learner_me<<<ME,128,0,stream>>>(mef, u, W2lat, W1lat, w2me, p1me, base, dflag);
    // meta Wo + residual + fused MN-learner
    gemm_wo_meta<<<gm,256,0,stream>>>(agg_m, wo_m, MN, z_m, meta_feat,
        u, W2lat, W1lat, p2mn, p1mn, dflag);

    // ---- big conv (fp8 kv) ----
    gemm_qkv<EPI_SCALE_GATHER,true,true><<<gN,256,0,stream>>>(feat, wqb, wkb, wvb,
        q, kv8, 0, kv8 + 128, 0, N, base_n2, p2mn, meta_node_id);
    edge_fused<<<(N+15)/16,256,0,stream>>>(rowptr, epack,
        meta_node_id, q, kv8, w2me, p1me, p1mn, base, z, aggb, N);
    gemm128m<EPI_RELU_RES,true,true,true><<<gN,256,0,stream>>>(aggb, wob, feat, N,
        z, nullptr, nullptr, nullptr, feat);

    // ---- readout ----
    readout<<<(BT*16+255)/256,256,0,stream>>>(target_idx, meta_node_id, feat, p1mn,
        base, acc, d_out, (b==NB-1) ? 1 : 0, invNB, BT, dflag);
  }
}

// Round 15
// 695.521 us; speedup vs baseline: 1.3202x; 1.1114x over previous
//
#include <hip/hip_runtime.h>
#include <hip/hip_bf16.h>
#include <hip/hip_fp8.h>

#define DD   128
#define HH   8

typedef short bf16x8 __attribute__((ext_vector_type(8)));
typedef float f32x4  __attribute__((ext_vector_type(4)));
typedef float f32x2  __attribute__((ext_vector_type(2)));

__device__ __forceinline__ float b2f(unsigned short v){
  union { unsigned int u; float f; } x; x.u = ((unsigned int)v) << 16; return x.f;
}
__device__ __forceinline__ unsigned short f2b(float f){
  __hip_bfloat16 h = __float2bfloat16(f);
  return *(unsigned short*)&h;
}
__device__ __forceinline__ unsigned char f2f8(float x){
  __hip_fp8_e4m3 h(x);
  return h.__x;
}
__device__ __forceinline__ float f82f(unsigned char b){
  __hip_fp8_e4m3 h; h.__x = b;
  return (float)h;
}
// 4 fp8 bytes (one u32) -> 4 floats; HW packed cvt when available.
__device__ __forceinline__ void cvt4(unsigned int w, float* o){
#if defined(__has_builtin)
# if __has_builtin(__builtin_amdgcn_cvt_pk_f32_fp8)
  f32x2 lo = __builtin_amdgcn_cvt_pk_f32_fp8((int)w, false);
  f32x2 hi = __builtin_amdgcn_cvt_pk_f32_fp8((int)w, true);
  o[0]=lo[0]; o[1]=lo[1]; o[2]=hi[0]; o[3]=hi[1];
  return;
# endif
#endif
  o[0]=f82f(w&0xff); o[1]=f82f((w>>8)&0xff);
  o[2]=f82f((w>>16)&0xff); o[3]=f82f((w>>24)&0xff);
}
struct __align__(8) us4 { unsigned short x,y,z,w; };

__device__ __forceinline__ float gld(const void* p, size_t i, bool f32){
  if (f32) return ((const float*)p)[i];
  return b2f(((const unsigned short*)p)[i]);
}

// Detect input float dtype. flag=1 -> inputs are f32.
__global__ __launch_bounds__(64) void k_detect(const unsigned short* __restrict__ emb,
                                               int* __restrict__ flag){
  int t = threadIdx.x;
  float m = 0.f;
  for (int i=t; i<128; i+=64){
    float x = fabsf(b2f(emb[i]));
    if (x < 1e30f) m = fmaxf(m, x);
  }
#pragma unroll
  for (int s=1;s<64;s<<=1) m = fmaxf(m, __shfl_xor(m, s, 64));
  if (t==0) *flag = (m > 1e4f) ? 1 : 0;
}

// ALL weight blocks (8 tensors x NB matrices) -> bf16 TRANSPOSED staging, one launch.
struct WPtrs { const void* p[8]; };
__global__ __launch_bounds__(256) void w_repack16(
    WPtrs W, unsigned short* __restrict__ stage, int NBt,
    const int* __restrict__ dflag)
{
  const bool wf32 = (*dflag) != 0;
  int idx = blockIdx.x >> 6;
  int ti = idx / NBt, bi = idx - ti*NBt;
  size_t bo = (size_t)bi*DD*DD;
  int i = (blockIdx.x & 63)*256 + threadIdx.x;
  int k = i >> 7, n = i & 127;
  float x;
  if (wf32) x = ((const float*)W.p[ti])[bo + i];
  else      x = b2f(((const unsigned short*)W.p[ti])[bo + i]);
  stage[(size_t)idx*DD*DD + n*DD + k] = f2b(x);
}

enum { EPI_STORE=0, EPI_SCALE_CONST=1, EPI_SCALE_GATHER=2, EPI_RELU=3,
       EPI_RELU_RES=4, EPI_RELU_RES2=5 };

#define APAD 136
#define CPAD 132

// C[M,128] = epi( prologue(A)[M,128] @ B[128,128] ), B bf16 TRANSPOSED ([n][k]).
// EPI_RELU_RES : C = relu(x) + Rb(bf16)                  [big Wo, OUTB=1]
// EPI_RELU_RES2: Cv = relu(x) f32; C2 += relu(x) (f32)   [meta Wo, OUTB=0]
template<int EPI, bool NORM, bool INB, bool OUTB>
__global__ __launch_bounds__(256) void gemm128m(
    const void* __restrict__ Av, const unsigned short* __restrict__ Bt,
    void* __restrict__ Cv, int M,
    const float* __restrict__ z, const float* __restrict__ svec,
    const float* __restrict__ P2, const int* __restrict__ gidx,
    const unsigned short* __restrict__ Rb,
    const float* __restrict__ Rf, float* __restrict__ C2)
{
  __shared__ unsigned short Asb[64*APAD];
  __shared__ unsigned short Btb[128*APAD];
  const int tid = threadIdx.x;
  const int wave = tid >> 6, lane = tid & 63;
  const int row0 = blockIdx.x * 64;

  {
    int r = tid >> 2, cb = (tid & 3) * 32;
    int gr = row0 + r;
    if (INB){
      const unsigned short* Ab = (const unsigned short*)Av;
#pragma unroll
      for (int j=0;j<4;j++){
        int c = cb + j*8;
        uint4 raw = make_uint4(0,0,0,0);
        if (gr < M) raw = *(const uint4*)(Ab + (size_t)gr*DD + c);
        if (NORM){
          float s = 0.f;
          if (gr < M) s = 1.0f/(z[(size_t)gr*HH + (c>>4)] + 1e-9f);
          const unsigned short* hw = (const unsigned short*)&raw;
          us4 o0, o1;
          o0.x=f2b(b2f(hw[0])*s); o0.y=f2b(b2f(hw[1])*s);
          o0.z=f2b(b2f(hw[2])*s); o0.w=f2b(b2f(hw[3])*s);
          o1.x=f2b(b2f(hw[4])*s); o1.y=f2b(b2f(hw[5])*s);
          o1.z=f2b(b2f(hw[6])*s); o1.w=f2b(b2f(hw[7])*s);
          *(us4*)&Asb[r*APAD + c] = o0; *(us4*)&Asb[r*APAD + c + 4] = o1;
        } else {
          *(uint4*)&Asb[r*APAD + c] = raw;
        }
      }
    } else {
      const float* Af = (const float*)Av;
#pragma unroll
      for (int j=0;j<8;j++){
        int c = cb + j*4;
        float4 val = make_float4(0.f,0.f,0.f,0.f);
        if (gr < M){
          val = *(const float4*)(Af + (size_t)gr*DD + c);
          if (NORM){
            float s = 1.0f / (z[(size_t)gr*HH + (c>>4)] + 1e-9f);
            val.x*=s; val.y*=s; val.z*=s; val.w*=s;
          }
        }
        us4 o; o.x=f2b(val.x); o.y=f2b(val.y); o.z=f2b(val.z); o.w=f2b(val.w);
        *(us4*)&Asb[r*APAD + c] = o;
      }
    }
  }
  {
    int n = tid >> 1, k0s = (tid & 1) * 64;
#pragma unroll
    for (int j=0;j<8;j++){
      uint4 raw = *(const uint4*)(Bt + (size_t)n*DD + k0s + j*8);
      *(uint4*)&Btb[n*APAD + k0s + j*8] = raw;
    }
  }
  __syncthreads();

  f32x4 acc[8];
#pragma unroll
  for (int t=0;t<8;t++) acc[t] = (f32x4){0.f,0.f,0.f,0.f};
  const int am = (lane & 15), kq = (lane >> 4) * 8;
#pragma unroll
  for (int k0=0;k0<128;k0+=32){
    bf16x8 a = *(bf16x8*)&Asb[(wave*16 + am)*APAD + k0 + kq];
#pragma unroll
    for (int t=0;t<8;t++){
      bf16x8 b = *(bf16x8*)&Btb[(t*16 + am)*APAD + k0 + kq];
      acc[t] = __builtin_amdgcn_mfma_f32_16x16x32_bf16(a, b, acc[t], 0,0,0);
    }
  }
  __syncthreads();
  float* Cls = (float*)Btb;
  {
    int rr = wave*16 + (lane>>4)*4;
    int cc = lane & 15;
#pragma unroll
    for (int t=0;t<8;t++)
#pragma unroll
      for (int r=0;r<4;r++)
        Cls[(rr + r)*CPAD + t*16 + cc] = acc[t][r];
  }
  __syncthreads();

  {
    int r = tid >> 2, cb = (tid & 3) * 32;
    int gr = row0 + r;
    if (gr < M){
#pragma unroll
      for (int j=0;j<8;j++){
        int c = cb + j*4;
        float4 o = *(float4*)&Cls[r*CPAD + c];
        if (EPI == EPI_SCALE_CONST){
          o.x*=svec[c+0]; o.y*=svec[c+1]; o.z*=svec[c+2]; o.w*=svec[c+3];
        } else if (EPI == EPI_SCALE_GATHER){
          int g = gidx[gr];
          const float* p = P2 + (size_t)g*DD + c;
          o.x*=(svec[c+0]+p[0]); o.y*=(svec[c+1]+p[1]);
          o.z*=(svec[c+2]+p[2]); o.w*=(svec[c+3]+p[3]);
        } else if (EPI == EPI_RELU){
          o.x=fmaxf(o.x,0.f); o.y=fmaxf(o.y,0.f); o.z=fmaxf(o.z,0.f); o.w=fmaxf(o.w,0.f);
        } else if (EPI == EPI_RELU_RES){
          us4 rb = *(const us4*)(Rb + (size_t)gr*DD + c);
          o.x=fmaxf(o.x,0.f)+b2f(rb.x); o.y=fmaxf(o.y,0.f)+b2f(rb.y);
          o.z=fmaxf(o.z,0.f)+b2f(rb.z); o.w=fmaxf(o.w,0.f)+b2f(rb.w);
        } else if (EPI == EPI_RELU_RES2){
          o.x=fmaxf(o.x,0.f); o.y=fmaxf(o.y,0.f); o.z=fmaxf(o.z,0.f); o.w=fmaxf(o.w,0.f);
          float4 rf = *(const float4*)(Rf + (size_t)gr*DD + c);
          *(float4*)(C2 + (size_t)gr*DD + c) =
              make_float4(o.x+rf.x, o.y+rf.y, o.z+rf.z, o.w+rf.w);
        }
        if (OUTB){
          us4 ob; ob.x=f2b(o.x); ob.y=f2b(o.y); ob.z=f2b(o.z); ob.w=f2b(o.w);
          *(us4*)((unsigned short*)Cv + (size_t)gr*DD + c) = ob;
        } else {
          *(float4*)((float*)Cv + (size_t)gr*DD + c) = o;
        }
      }
    }
  }
}

// Fused Q/K/V gemm. FP8KV: phases 1/2 write fp8 (x8 scale) into 256B/row kv buffer.
template<int EPIQ, bool INB, bool FP8KV>
__global__ __launch_bounds__(256) void gemm_qkv(
    const void* __restrict__ Av,
    const unsigned short* __restrict__ Btq, const unsigned short* __restrict__ Btk,
    const unsigned short* __restrict__ Btv,
    void* __restrict__ Cq, void* __restrict__ Ck, int stK,
    void* __restrict__ Cvo, int stV, int M,
    const float* __restrict__ svec, const float* __restrict__ P2,
    const int* __restrict__ gidx)
{
  __shared__ unsigned short Asb[64*APAD];
  __shared__ unsigned short Btb[128*APAD];
  const int tid = threadIdx.x;
  const int wave = tid >> 6, lane = tid & 63;
  const int row0 = blockIdx.x * 64;

  {
    int r = tid >> 2, cb = (tid & 3) * 32;
    int gr = row0 + r;
    if (INB){
      const unsigned short* Ab = (const unsigned short*)Av;
#pragma unroll
      for (int j=0;j<4;j++){
        int c = cb + j*8;
        uint4 raw = make_uint4(0,0,0,0);
        if (gr < M) raw = *(const uint4*)(Ab + (size_t)gr*DD + c);
        *(uint4*)&Asb[r*APAD + c] = raw;
      }
    } else {
      const float* Af = (const float*)Av;
#pragma unroll
      for (int j=0;j<8;j++){
        int c = cb + j*4;
        float4 val = make_float4(0.f,0.f,0.f,0.f);
        if (gr < M) val = *(const float4*)(Af + (size_t)gr*DD + c);
        us4 o; o.x=f2b(val.x); o.y=f2b(val.y); o.z=f2b(val.z); o.w=f2b(val.w);
        *(us4*)&Asb[r*APAD + c] = o;
      }
    }
  }

  const unsigned short* Bts[3] = {Btq, Btk, Btv};
  void* Cs[3] = {Cq, Ck, Cvo};
  const int sts[3] = {DD, stK, stV};
  const int am = (lane & 15), kq = (lane >> 4) * 8;

  for (int ph=0; ph<3; ph++){
    {
      int n = tid >> 1, k0s = (tid & 1) * 64;
      const unsigned short* Bt = Bts[ph];
#pragma unroll
      for (int j=0;j<8;j++){
        uint4 raw = *(const uint4*)(Bt + (size_t)n*DD + k0s + j*8);
        *(uint4*)&Btb[n*APAD + k0s + j*8] = raw;
      }
    }
    __syncthreads();
    f32x4 acc[8];
#pragma unroll
    for (int t=0;t<8;t++) acc[t] = (f32x4){0.f,0.f,0.f,0.f};
#pragma unroll
    for (int k0=0;k0<128;k0+=32){
      bf16x8 a = *(bf16x8*)&Asb[(wave*16 + am)*APAD + k0 + kq];
#pragma unroll
      for (int t=0;t<8;t++){
        bf16x8 b = *(bf16x8*)&Btb[(t*16 + am)*APAD + k0 + kq];
        acc[t] = __builtin_amdgcn_mfma_f32_16x16x32_bf16(a, b, acc[t], 0,0,0);
      }
    }
    __syncthreads();
    float* Cls = (float*)Btb;
    {
      int rr = wave*16 + (lane>>4)*4;
      int cc = lane & 15;
#pragma unroll
      for (int t=0;t<8;t++)
#pragma unroll
        for (int r=0;r<4;r++)
          Cls[(rr + r)*CPAD + t*16 + cc] = acc[t][r];
    }
    __syncthreads();
    {
      int r = tid >> 2, cb = (tid & 3) * 32;
      int gr = row0 + r;
      if (gr < M){
#pragma unroll
        for (int j=0;j<8;j++){
          int c = cb + j*4;
          float4 o = *(float4*)&Cls[r*CPAD + c];
          if (ph == 0){
            if (EPIQ == EPI_SCALE_GATHER){
              int g = gidx[gr];
              const float* p = P2 + (size_t)g*DD + c;
              o.x*=(svec[c+0]+p[0]); o.y*=(svec[c+1]+p[1]);
              o.z*=(svec[c+2]+p[2]); o.w*=(svec[c+3]+p[3]);
            } else {
              o.x*=svec[c+0]; o.y*=svec[c+1]; o.z*=svec[c+2]; o.w*=svec[c+3];
            }
          }
          if (FP8KV && ph > 0){
            unsigned char* Cb = (unsigned char*)Cs[ph];
            uchar4 ob;
            ob.x=f2f8(o.x*8.f); ob.y=f2f8(o.y*8.f);
            ob.z=f2f8(o.z*8.f); ob.w=f2f8(o.w*8.f);
            *(uchar4*)(Cb + (size_t)gr*256 + c) = ob;
          } else {
            us4 ob; ob.x=f2b(o.x); ob.y=f2b(o.y); ob.z=f2b(o.z); ob.w=f2b(o.w);
            *(us4*)((unsigned short*)Cs[ph] + (size_t)gr*sts[ph] + c) = ob;
          }
        }
      }
    }
    __syncthreads();
  }
}

// Static param-name graph -> base params.
__global__ __launch_bounds__(256) void k_static(
    const void* __restrict__ emb, const int* __restrict__ svals,
    const int* __restrict__ ssrc, const int* __restrict__ sdst,
    const void* __restrict__ u, const void* __restrict__ W2,
    const void* __restrict__ W1, float* __restrict__ base, int nsrc,
    const int* __restrict__ dflag)
{
  __shared__ float sagg[15][128];
  __shared__ float ssc[15][16];
  __shared__ float sww[15][16];
  const bool wf32 = (*dflag) != 0;
  const int t = threadIdx.x;
  for (int i=t;i<15*128;i+=256) ((float*)sagg)[i]=0.f;
  __syncthreads();
  if (t < 128){
    for (int i=0;i<nsrc;i++){
      int row = sdst[i]; int vr = svals[ssrc[i]];
      sagg[row][t] += gld(emb, (size_t)vr*DD + t, wf32);
    }
  }
  __syncthreads();
  if (t < 240){
    int n = t>>4, l = t&15;
    float a=0.f;
    for (int d=0;d<128;d++) a += sagg[n][d]*gld(u, l*128+d, wf32);
    ssc[n][l] = a * 0.08838834764831845f;
  }
  __syncthreads();
  if (t < 15){
    float mx=-1e30f;
    for (int l=0;l<16;l++) mx = fmaxf(mx, ssc[t][l]);
    float s=0.f;
    for (int l=0;l<16;l++){ float e=__expf(ssc[t][l]-mx); sww[t][l]=e; s+=e; }
    float inv = 1.f/s;
    for (int l=0;l<16;l++) sww[t][l]*=inv;
  }
  __syncthreads();
  if (t < 8){
    float a=0.f,b=0.f,c=0.f;
    for (int l=0;l<16;l++){
      float wv = gld(W1, l*8+t, wf32);
      a += sww[0][l]*wv; b += sww[3][l]*wv; c += sww[9][l]*wv;
    }
    base[t]=a; base[8+t]=b; base[16+t]=c;
  }
  if (t < 128){
    float a=0.f,b=0.f;
    for (int l=0;l<16;l++){
      float wv = gld(W2, l*128+t, wf32);
      a += sww[6][l]*wv; b += sww[12][l]*wv;
    }
    base[24+t]=a; base[152+t]=b;
  }
}

// Merged gather: big graph rows -> bf16 feat; meta rows -> f32 meta_feat.
__global__ __launch_bounds__(256) void gather_rows2(
    const void* __restrict__ emb,
    const int* __restrict__ valsB, unsigned short* __restrict__ featB, int nB,
    const int* __restrict__ valsM, float* __restrict__ featM, int nM,
    const int* __restrict__ dflag)
{
  const bool wf32 = (*dflag) != 0;
  int i = blockIdx.x*256 + threadIdx.x;
  bool big = (i < nB*16);
  int i2 = big ? i : (i - nB*16);
  if (!big && i2 >= nM*16) return;
  int r = i2>>4, c = (i2&15)*8;
  int vr = big ? valsB[r] : valsM[r];
  float vb[8];
  if (wf32){
    float4 f0 = *(const float4*)((const float*)emb + (size_t)vr*DD + c);
    float4 f1 = *(const float4*)((const float*)emb + (size_t)vr*DD + c + 4);
    vb[0]=f0.x; vb[1]=f0.y; vb[2]=f0.z; vb[3]=f0.w;
    vb[4]=f1.x; vb[5]=f1.y; vb[6]=f1.z; vb[7]=f1.w;
  } else {
    uint4 raw = *(const uint4*)((const unsigned short*)emb + (size_t)vr*DD + c);
    const unsigned short* hw = (const unsigned short*)&raw;
#pragma unroll
    for (int j=0;j<8;j++) vb[j] = b2f(hw[j]);
  }
  if (big){
    unsigned short* d = featB + (size_t)r*DD + c;
    us4 o0, o1;
    o0.x=f2b(vb[0]); o0.y=f2b(vb[1]); o0.z=f2b(vb[2]); o0.w=f2b(vb[3]);
    o1.x=f2b(vb[4]); o1.y=f2b(vb[5]); o1.z=f2b(vb[6]); o1.w=f2b(vb[7]);
    *(us4*)d = o0; *(us4*)(d+4) = o1;
  } else {
    float* d = featM + (size_t)r*DD + c;
    *(float4*)d     = make_float4(vb[0],vb[1],vb[2],vb[3]);
    *(float4*)(d+4) = make_float4(vb[4],vb[5],vb[6],vb[7]);
  }
}

__global__ __launch_bounds__(256) void zeroi(int* __restrict__ p, int n){
  int i = blockIdx.x*256 + threadIdx.x;
  if (i < n) p[i] = 0;
}

// ---------------- merged CSR build (big + meta graphs) ----------------
__global__ __launch_bounds__(256) void k_hist2(
    const int* __restrict__ dstB, const int* __restrict__ dstM,
    int* __restrict__ degB, int* __restrict__ degM, int E, int ME, int nbE){
  int b = blockIdx.x, t = threadIdx.x;
  if (b < nbE){ int i = b*256+t; if (i < E) atomicAdd(&degB[dstB[i]], 1); }
  else { int i = (b-nbE)*256+t; if (i < ME) atomicAdd(&degM[dstM[i]], 1); }
}

__global__ __launch_bounds__(256) void k_scan1b(
    const int* __restrict__ degB, int* __restrict__ rpB, int* __restrict__ bsB,
    int nB, int nbB,
    const int* __restrict__ degM, int* __restrict__ rpM, int* __restrict__ bsM,
    int nM){
  __shared__ int ls[256];
  int blk = blockIdx.x, t = threadIdx.x;
  const int* deg; int* rowptr; int* bsum; int n; int b;
  if (blk < nbB){ deg=degB; rowptr=rpB; bsum=bsB; n=nB; b=blk; }
  else          { deg=degM; rowptr=rpM; bsum=bsM; n=nM; b=blk-nbB; }
  int base = b*1024 + t*4;
  int v0 = (base+0<n)?deg[base+0]:0;
  int v1 = (base+1<n)?deg[base+1]:0;
  int v2 = (base+2<n)?deg[base+2]:0;
  int v3 = (base+3<n)?deg[base+3]:0;
  int tsum = v0+v1+v2+v3;
  ls[t] = tsum; __syncthreads();
  for (int o=1;o<256;o<<=1){
    int x = (t>=o) ? ls[t-o] : 0;
    __syncthreads();
    ls[t] += x;
    __syncthreads();
  }
  int excl = ls[t]-tsum;
  if (t==255) bsum[b] = ls[255];
  if (base+0<n) rowptr[base+0]=excl;
  if (base+1<n) rowptr[base+1]=excl+v0;
  if (base+2<n) rowptr[base+2]=excl+v0+v1;
  if (base+3<n) rowptr[base+3]=excl+v0+v1+v2;
}

// scan3 with in-block prefix of block sums (scan2 merged in).
__global__ __launch_bounds__(256) void k_scan3b(
    int* __restrict__ rpB, const int* __restrict__ bsB, int* __restrict__ curB,
    int nB, int nb3B, int nbsB,
    int* __restrict__ rpM, const int* __restrict__ bsM, int* __restrict__ curM,
    int nM, int nbsM){
  __shared__ int spre;
  int blk = blockIdx.x, t = threadIdx.x;
  if (blk < nb3B){
    if (t == 0){
      int chunk = blk >> 2;
      int pre = 0;
      for (int j=0;j<chunk;j++) pre += bsB[j];
      spre = pre;
      if (blk == 0){
        int tot = 0;
        for (int j=0;j<nbsB;j++) tot += bsB[j];
        rpB[nB] = tot;
      }
    }
    __syncthreads();
    int i = blk*256 + t;
    if (i < nB){ int r = rpB[i] + spre; rpB[i] = r; curB[i] = r; }
  } else {
    int b2 = blk - nb3B;
    if (t == 0){
      int chunk = b2 >> 2;
      int pre = 0;
      for (int j=0;j<chunk;j++) pre += bsM[j];
      spre = pre;
      if (b2 == 0){
        int tot = 0;
        for (int j=0;j<nbsM;j++) tot += bsM[j];
        rpM[nM] = tot;
      }
    }
    __syncthreads();
    int i = b2*256 + t;
    if (i < nM){ int r = rpM[i] + spre; rpM[i] = r; curM[i] = r; }
  }
}

// scatter. Big graph: pack (src | meid<<17) into one int.
__global__ __launch_bounds__(256) void k_scatter2(
    const int* __restrict__ dstB, const int* __restrict__ srcB,
    const int* __restrict__ auxB, int* __restrict__ curB,
    int* __restrict__ epackB, int E, int nbE,
    const int* __restrict__ dstM, const int* __restrict__ srcM,
    int* __restrict__ curM, int* __restrict__ esrcM, int* __restrict__ eauxM,
    int ME){
  int blk = blockIdx.x, t = threadIdx.x;
  if (blk < nbE){
    int e = blk*256 + t;
    if (e < E){
      int p = atomicAdd(&curB[dstB[e]], 1);
      epackB[p] = srcB[e] | (auxB[e] << 17);
    }
  } else {
    int e = (blk-nbE)*256 + t;
    if (e < ME){
      int p = atomicAdd(&curM[dstM[e]], 1);
      esrcM[p] = srcM[e];
      eauxM[p] = e;
    }
  }
}

// ---------------- meta-graph edges: CSR, atomic-free, writes mef ----------------
__global__ __launch_bounds__(256) void edge_meta_csr(
    const int* __restrict__ rowptr, const int* __restrict__ esrc,
    const int* __restrict__ eorig,
    const unsigned short* __restrict__ qm, const unsigned short* __restrict__ kfm,
    const unsigned short* __restrict__ vm,
    const float* __restrict__ base, unsigned short* __restrict__ mef,
    float* __restrict__ z, float* __restrict__ agg, int NM)
{
  int d = blockIdx.x*4 + (threadIdx.x>>6);
  if (d >= NM) return;
  int lane = threadIdx.x & 63;
  const float* be2 = base+152; const float* be1 = base+16; const float* bn1 = base+8;
  size_t dq = (size_t)d*DD;
  float q0 = b2f(qm[dq+lane]), q1 = b2f(qm[dq+64+lane]);
  float w0 = be2[lane], w1 = be2[64+lane];
  int h0 = lane>>4, h1 = h0+4;
  float bias0 = be1[h0] + bn1[h0];
  float bias1 = be1[h1] + bn1[h1];
  float z0=0.f, z1=0.f, a0=0.f, a1=0.f;
  int i0 = rowptr[d], i1 = rowptr[d+1];
  for (int i=i0; i<i1; i++){
    int s = esrc[i], e = eorig[i];
    size_t so=(size_t)s*DD, eo=(size_t)e*DD;
    float ke0 = b2f(kfm[so+lane])    * w0;
    float ke1 = b2f(kfm[so+64+lane]) * w1;
    mef[eo+lane]=f2b(ke0); mef[eo+64+lane]=f2b(ke1);
    float p0 = q0*ke0, p1 = q1*ke1;
#pragma unroll
    for (int m=1;m<16;m<<=1){ p0 += __shfl_xor(p0,m,64); p1 += __shfl_xor(p1,m,64); }
    float e0 = __expf(p0*0.25f + bias0);
    float e1 = __expf(p1*0.25f + bias1);
    z0 += e0; z1 += e1;
    a0 += e0*b2f(vm[so+lane]);
    a1 += e1*b2f(vm[so+64+lane]);
  }
  if ((lane&15)==0){ z[(size_t)d*HH+h0] = z0; z[(size_t)d*HH+h1] = z1; }
  agg[dq+lane]    = a0;
  agg[dq+64+lane] = a1;
}

// Fused meta-learner over [meta_out (Ma rows, f32) | mef (bf16)] — wide launch.
__global__ __launch_bounds__(128) void learner2(
    const float* __restrict__ Xa, const unsigned short* __restrict__ Xb, int Ma,
    const void* __restrict__ u, const void* __restrict__ W2,
    const void* __restrict__ W1,
    float* __restrict__ p2a, float* __restrict__ p1a,
    unsigned short* __restrict__ w2me, unsigned short* __restrict__ p1b,
    const float* __restrict__ base, const int* __restrict__ dflag)
{
  __shared__ float sX[128];
  __shared__ float st[16];
  __shared__ float sw[16];
  const bool wf32 = (*dflag) != 0;
  const int blk = blockIdx.x, t = threadIdx.x;
  const bool isB = (blk >= Ma);
  const int m = isB ? (blk - Ma) : blk;
  if (isB) sX[t] = b2f(Xb[(size_t)m*DD + t]);
  else     sX[t] = Xa[(size_t)m*DD + t];
  __syncthreads();
  int l = t>>3, j = t&7;
  float part = 0.f;
  for (int d=j*16; d<j*16+16; d++) part += sX[d]*gld(u, l*128+d, wf32);
  part += __shfl_xor(part,1,64); part += __shfl_xor(part,2,64); part += __shfl_xor(part,4,64);
  if (j==0) st[l] = part * 0.08838834764831845f;
  __syncthreads();
  float mx=-1e30f;
  for (int i=0;i<16;i++) mx = fmaxf(mx, st[i]);
  float ssum=0.f;
  for (int i=0;i<16;i++) ssum += __expf(st[i]-mx);
  float inv = 1.f/ssum;
  if (t<16) sw[t] = __expf(st[t]-mx)*inv;
  __syncthreads();
  float a=0.f;
  for (int i=0;i<16;i++) a += sw[i]*gld(W2, i*128+t, wf32);
  if (isB) w2me[(size_t)m*DD+t] = f2b(base[152+t] + a);
  else     p2a[(size_t)m*DD+t] = a;
  if (t<8){
    float bb=0.f;
    for (int i=0;i<16;i++) bb += sw[i]*gld(W1, i*8+t, wf32);
    if (isB) p1b[(size_t)m*HH+t] = f2b(bb);
    else     p1a[(size_t)m*HH+t] = bb;
  }
}

// ---------------- big-graph: fused scores+agg, fp8 kv, packed indices ----------
__global__ __launch_bounds__(256) void edge_fused(
    const int* __restrict__ rowptr, const int* __restrict__ epack,
    const int* __restrict__ mnid,
    const unsigned short* __restrict__ q, const unsigned char* __restrict__ kv8,
    const unsigned short* __restrict__ w2me, const unsigned short* __restrict__ p1me,
    const float* __restrict__ p1mn, const float* __restrict__ base,
    float* __restrict__ z, unsigned short* __restrict__ aggb, int N)
{
  int wv = blockIdx.x*4 + (threadIdx.x>>6);
  int d0 = wv*4;
  if (d0 >= N) return;
  int lane = threadIdx.x & 63;
  int grp = lane >> 4, l16 = lane & 15;
  int c8 = l16 * 8;
  int h = l16 >> 1;
  const float* be1 = base+16; const float* bn1 = base+8;
  const float biash = be1[h] + bn1[h];

  for (int dd=0; dd<4; dd++){
    int d = d0 + dd;
    if (d >= N) break;
    size_t dq = (size_t)d*DD;
    float qv[8];
    {
      uint4 qraw = *(const uint4*)(q + dq + c8);
      const unsigned short* qh = (const unsigned short*)&qraw;
#pragma unroll
      for (int j=0;j<8;j++) qv[j] = b2f(qh[j])*0.03125f;  // 0.25 * 1/8 (k fp8 scale)
    }
    int mn = mnid[d];
    float bias = biash + p1mn[(size_t)mn*HH + h];

    float zh = 0.f;
    float a[8];
#pragma unroll
    for (int j=0;j<8;j++) a[j] = 0.f;

    int i0 = rowptr[d], i1 = rowptr[d+1];
    int i = i0 + grp;
    for (; i + 4 < i1; i += 8){
      unsigned int v0p = (unsigned int)epack[i];
      unsigned int v1p = (unsigned int)epack[i+4];
      int s0 = v0p & 0x1FFFF, me0 = v0p >> 17;
      int s1 = v1p & 0x1FFFF, me1 = v1p >> 17;
      size_t kvo0 = (size_t)s0*256, mo0 = (size_t)me0*DD;
      size_t kvo1 = (size_t)s1*256, mo1 = (size_t)me1*DD;
      uint2 kraw0 = *(const uint2*)(kv8 + kvo0 + c8);
      uint2 vraw0 = *(const uint2*)(kv8 + kvo0 + 128 + c8);
      uint4 wraw0 = *(const uint4*)(w2me + mo0 + c8);
      float pm0 = b2f(p1me[(size_t)me0*HH + h]);
      uint2 kraw1 = *(const uint2*)(kv8 + kvo1 + c8);
      uint2 vraw1 = *(const uint2*)(kv8 + kvo1 + 128 + c8);
      uint4 wraw1 = *(const uint4*)(w2me + mo1 + c8);
      float pm1 = b2f(p1me[(size_t)me1*HH + h]);
      float k0f[8], v0f[8], k1f[8], v1f[8];
      cvt4(kraw0.x, k0f); cvt4(kraw0.y, k0f+4);
      cvt4(vraw0.x, v0f); cvt4(vraw0.y, v0f+4);
      cvt4(kraw1.x, k1f); cvt4(kraw1.y, k1f+4);
      cvt4(vraw1.x, v1f); cvt4(vraw1.y, v1f+4);
      const unsigned short* wh0 = (const unsigned short*)&wraw0;
      const unsigned short* wh1 = (const unsigned short*)&wraw1;
      float pA = 0.f, pB = 0.f;
#pragma unroll
      for (int j=0;j<8;j++){
        pA += qv[j]*(k0f[j]*b2f(wh0[j]));
        pB += qv[j]*(k1f[j]*b2f(wh1[j]));
      }
      pA += __shfl_xor(pA, 1, 64);
      pB += __shfl_xor(pB, 1, 64);
      float ex0 = __expf(pA + bias + pm0);
      float ex1 = __expf(pB + bias + pm1);
      zh += ex0 + ex1;
      float ev0 = ex0*0.125f, ev1 = ex1*0.125f;
#pragma unroll
      for (int j=0;j<8;j++) a[j] += ev0*v0f[j] + ev1*v1f[j];
    }
    if (i < i1){
      unsigned int vp = (unsigned int)epack[i];
      int s = vp & 0x1FFFF, me = vp >> 17;
      size_t kvo = (size_t)s*256, mo = (size_t)me*DD;
      uint2 kraw = *(const uint2*)(kv8 + kvo + c8);
      uint2 vraw = *(const uint2*)(kv8 + kvo + 128 + c8);
      uint4 wraw = *(const uint4*)(w2me + mo + c8);
      float pm = b2f(p1me[(size_t)me*HH + h]);
      float kf[8], vf[8];
      cvt4(kraw.x, kf); cvt4(kraw.y, kf+4);
      cvt4(vraw.x, vf); cvt4(vraw.y, vf+4);
      const unsigned short* wh = (const unsigned short*)&wraw;
      float p = 0.f;
#pragma unroll
      for (int j=0;j<8;j++) p += qv[j]*(kf[j]*b2f(wh[j]));
      p += __shfl_xor(p, 1, 64);
      float ex = __expf(p + bias + pm);
      zh += ex;
      float ev = ex*0.125f;
#pragma unroll
      for (int j=0;j<8;j++) a[j] += ev*vf[j];
    }

    zh += __shfl_xor(zh, 16, 64); zh += __shfl_xor(zh, 32, 64);
#pragma unroll
    for (int j=0;j<8;j++){
      a[j] += __shfl_xor(a[j], 16, 64);
      a[j] += __shfl_xor(a[j], 32, 64);
    }
    if (grp == 0){
      us4 o0, o1;
      o0.x=f2b(a[0]); o0.y=f2b(a[1]); o0.z=f2b(a[2]); o0.w=f2b(a[3]);
      o1.x=f2b(a[4]); o1.y=f2b(a[5]); o1.z=f2b(a[6]); o1.w=f2b(a[7]);
      *(us4*)(aggb + dq + c8)     = o0;
      *(us4*)(aggb + dq + c8 + 4) = o1;
      if ((l16 & 1) == 0) z[(size_t)d*HH + h] = zh;
    }
  }
}

// One 16-lane group per target; vectorized feat row read + shuffle reduce.
__global__ __launch_bounds__(256) void readout(
    const int* __restrict__ tgt, const int* __restrict__ mnid,
    const unsigned short* __restrict__ featb, const float* __restrict__ p1mn,
    const float* __restrict__ base, float* __restrict__ acc,
    void* __restrict__ out, int last, float invNB, int BT,
    const int* __restrict__ dflag)
{
  int t = blockIdx.x*256 + threadIdx.x;
  int ti = t >> 4, l16 = t & 15;
  if (ti >= BT) return;
  int idx = tgt[ti]; int mn = mnid[idx];
  int h = l16 >> 1;
  float tw = base[h] + p1mn[(size_t)mn*HH + h];
  uint4 raw = *(const uint4*)(featb + (size_t)idx*DD + l16*8);
  const unsigned short* hw = (const unsigned short*)&raw;
  float s = 0.f;
#pragma unroll
  for (int j=0;j<8;j++) s += b2f(hw[j]);
  float part = tw * s;
  part += __shfl_xor(part, 1, 64);
  part += __shfl_xor(part, 2, 64);
  part += __shfl_xor(part, 4, 64);
  part += __shfl_xor(part, 8, 64);
  if (l16 == 0){
    if (!last) acc[ti] = part;
    else {
      float r = (acc[ti] + part) * invNB;
      if ((*dflag) != 0) ((float*)out)[ti] = r;
      else ((__hip_bfloat16*)out)[ti] = __float2bfloat16(r);
    }
  }
}

extern "C" void kernel_launch(void* const* d_in, const int* in_sizes, int n_in,
                              void* d_out, int out_size, void* d_ws, size_t ws_size,
                              hipStream_t stream) {
  const void* emb   = d_in[0];
  const void* u     = d_in[1];
  const void* W2lat = d_in[2];
  const void* W1lat = d_in[3];
  WPtrs wptrs;
  for (int i=0;i<8;i++) wptrs.p[i] = d_in[4+i];
  const int* node_vals      = (const int*)d_in[12];
  const int* meta_node_vals = (const int*)d_in[13];
  const int* src            = (const int*)d_in[14];
  const int* dst            = (const int*)d_in[15];
  const int* meta_src       = (const int*)d_in[16];
  const int* meta_dst       = (const int*)d_in[17];
  const int* meta_node_id   = (const int*)d_in[18];
  const int* meta_edge_id   = (const int*)d_in[19];
  const int* target_idx     = (const int*)d_in[20];
  const int* static_vals    = (const int*)d_in[21];
  const int* static_src     = (const int*)d_in[22];
  const int* static_dst     = (const int*)d_in[23];

  const int N  = in_sizes[12];
  const int MN = in_sizes[13];
  const int E  = in_sizes[14];
  const int ME = in_sizes[16];
  const int BT = in_sizes[20];
  const int NSRC = in_sizes[22];
  const int NB = in_sizes[8] / (DD*DD);

  float* ws = (float*)d_ws;
  size_t off = 0;
  auto allocf = [&](size_t n){ float* p = ws + off; off += n; return p; };
  auto allocb = [&](size_t n){ unsigned short* p = (unsigned short*)(ws + off); off += (n+1)/2; return p; };
  auto alloci = [&](size_t n){ int* p = (int*)(ws + off); off += n; return p; };
  int*            dflag = (int*)ws; off += 4;
  unsigned short* feat  = allocb((size_t)N*DD);
  unsigned short* q     = allocb((size_t)N*DD);
  unsigned char*  kv8   = (unsigned char*)allocf((size_t)N*64);  // N x 256B fp8 rows
  unsigned short* aggb  = allocb((size_t)N*DD);
  float*          z     = allocf((size_t)N*HH);
  float*          meta_feat= allocf((size_t)MN*DD);
  float*          agg_m = allocf((size_t)MN*DD);
  float*          z_m   = allocf((size_t)MN*HH);
  unsigned short* q_m   = allocb((size_t)MN*DD);
  unsigned short* kf_m  = allocb((size_t)MN*DD);
  unsigned short* v_m   = allocb((size_t)MN*DD);
  float*          meta_out = allocf((size_t)MN*DD);
  unsigned short* mef   = allocb((size_t)ME*DD);
  float*          p2mn  = allocf((size_t)MN*DD);
  float*          p1mn  = allocf((size_t)MN*HH);
  unsigned short* w2me  = allocb((size_t)ME*DD);
  unsigned short* p1me  = allocb((size_t)ME*HH);
  float*          base  = allocf(280);
  float*          acc   = allocf((size_t)BT);
  unsigned short* wstage= allocb((size_t)8*NB*DD*DD);
  int*            rowptr= alloci((size_t)N+1);
  int*            cursor= alloci((size_t)N);
  int*            epack = alloci((size_t)E);
  int*            rowptr_m= alloci((size_t)MN+1);
  int*            cursor_m= alloci((size_t)MN);
  int*            esrc_m  = alloci((size_t)ME);
  int*            eorig_m = alloci((size_t)ME);
  int*            degAll  = alloci((size_t)(N+MN));
  int*            deg     = degAll;
  int*            deg_m   = degAll + N;
  const int nb_scan   = (N + 1023)/1024;
  const int nb_scan_m = (MN + 1023)/1024;
  int*            bsum   = alloci((size_t)nb_scan);
  int*            bsum_m = alloci((size_t)nb_scan_m);
  (void)ws_size; (void)n_in; (void)out_size;

  const float* base_n2 = base + 24;

  k_detect<<<1,64,0,stream>>>((const unsigned short*)emb, dflag);
  k_static<<<1,256,0,stream>>>(emb, static_vals, static_src, static_dst,
                               u, W2lat, W1lat, base, NSRC, dflag);
  gather_rows2<<<((N+MN)*16+255)/256,256,0,stream>>>(emb, node_vals, feat, N,
      meta_node_vals, meta_feat, MN, dflag);

  const int nbE  = (E+255)/256, nbME = (ME+255)/256;
  const int nb3B = (N+255)/256, nb3M = (MN+255)/256;
  zeroi<<<(N+MN+255)/256,256,0,stream>>>(degAll, N+MN);
  k_hist2<<<nbE+nbME,256,0,stream>>>(dst, meta_dst, deg, deg_m, E, ME, nbE);
  k_scan1b<<<nb_scan+nb_scan_m,256,0,stream>>>(deg, rowptr, bsum, N, nb_scan,
      deg_m, rowptr_m, bsum_m, MN);
  k_scan3b<<<nb3B+nb3M,256,0,stream>>>(rowptr, bsum, cursor, N, nb3B, nb_scan,
      rowptr_m, bsum_m, cursor_m, MN, nb_scan_m);
  k_scatter2<<<nbE+nbME,256,0,stream>>>(dst, src, meta_edge_id, cursor,
      epack, E, nbE, meta_dst, meta_src, cursor_m, esrc_m, eorig_m, ME);

  w_repack16<<<8*NB*64,256,0,stream>>>(wptrs, wstage, NB, dflag);

  const int gm = (MN+63)/64;
  const int gN = (N+63)/64;
  const float invNB = 1.0f/(float)NB;

  for (int b=0;b<NB;b++){
    const unsigned short* wq_m = wstage + (size_t)(0*NB+b)*DD*DD;
    const unsigned short* wk_m = wstage + (size_t)(1*NB+b)*DD*DD;
    const unsigned short* wv_m = wstage + (size_t)(2*NB+b)*DD*DD;
    const unsigned short* wo_m = wstage + (size_t)(3*NB+b)*DD*DD;
    const unsigned short* wqb  = wstage + (size_t)(4*NB+b)*DD*DD;
    const unsigned short* wkb  = wstage + (size_t)(5*NB+b)*DD*DD;
    const unsigned short* wvb  = wstage + (size_t)(6*NB+b)*DD*DD;
    const unsigned short* wob  = wstage + (size_t)(7*NB+b)*DD*DD;

    // ---- meta conv (CSR, atomic-free) ----
    gemm_qkv<EPI_SCALE_CONST,false,false><<<gm,256,0,stream>>>(meta_feat,
        wq_m, wk_m, wv_m, q_m, kf_m, DD, v_m, DD, MN, base_n2, nullptr, nullptr);
    edge_meta_csr<<<(MN+3)/4,256,0,stream>>>(rowptr_m, esrc_m, eorig_m,
        q_m, kf_m, v_m, base, mef, z_m, agg_m, MN);
    // meta Wo: meta_out = relu(norm(agg_m)@Wo) (f32); meta_feat += relu(...)
    gemm128m<EPI_RELU_RES2,true,false,false><<<gm,256,0,stream>>>(agg_m, wo_m,
        meta_out, MN, z_m, nullptr, nullptr, nullptr, nullptr, meta_feat, meta_feat);
    // wide fused learners: MN rows (f32 meta_out) + ME rows (bf16 mef)
    learner2<<<MN+ME,128,0,stream>>>(meta_out, mef, MN, u, W2lat, W1lat,
        p2mn, p1mn, w2me, p1me, base, dflag);

    // ---- big conv (fp8 kv) ----
    gemm_qkv<EPI_SCALE_GATHER,true,true><<<gN,256,0,stream>>>(feat, wqb, wkb, wvb,
        q, kv8, 0, kv8 + 128, 0, N, base_n2, p2mn, meta_node_id);
    edge_fused<<<(N+15)/16,256,0,stream>>>(rowptr, epack,
        meta_node_id, q, kv8, w2me, p1me, p1mn, base, z, aggb, N);
    gemm128m<EPI_RELU_RES,true,true,true><<<gN,256,0,stream>>>(aggb, wob, feat, N,
        z, nullptr, nullptr, nullptr, feat, nullptr, nullptr);

    // ---- readout ----
    readout<<<(BT*16+255)/256,256,0,stream>>>(target_idx, meta_node_id, feat, p1mn,
        base, acc, d_out, (b==NB-1) ? 1 : 0, invNB, BT, dflag);
  }
}